// Round 6
// baseline (197.320 us; speedup 1.0000x reference)
//
#include <hip/hip_runtime.h>
#include <stdint.h>

#define DEVI __device__ __forceinline__

typedef __attribute__((ext_vector_type(8))) short bf16x8;
typedef __attribute__((ext_vector_type(4))) float f32x4;
typedef __attribute__((ext_vector_type(4))) float flt4;
typedef __attribute__((ext_vector_type(8))) unsigned short u16x8;
typedef __attribute__((ext_vector_type(4))) unsigned short u16x4;

DEVI unsigned short f2bf(float f){
  union{float f;uint32_t u;}v; v.f=f;
  uint32_t u=v.u;
  u += 0x7FFFu + ((u>>16)&1u);
  return (unsigned short)(u>>16);
}

DEVI uint32_t cvt_pk_bf16(float lo, float hi){
  uint32_t r;
  asm("v_cvt_pk_bf16_f32 %0, %1, %2" : "=v"(r) : "v"(lo), "v"(hi));
  return r;
}

DEVI float fexp2(float x){
#if __has_builtin(__builtin_amdgcn_exp2f)
  return __builtin_amdgcn_exp2f(x);
#else
  return exp2f(x);
#endif
}

DEVI void gload16(const void* g, void* l){
  __builtin_amdgcn_global_load_lds((const __attribute__((address_space(1))) void*)g,
                                   (__attribute__((address_space(3))) void*)l, 16, 0, 0);
}

// ---------------- fp32 -> bf16 convert, z-batched over {q,k,v} ----------------
__global__ void cvt3_k(const float* __restrict__ q, const float* __restrict__ k,
                       const float* __restrict__ v, unsigned short* __restrict__ qb,
                       unsigned short* __restrict__ kb, unsigned short* __restrict__ vb, int n8){
  int i = blockIdx.x*256 + threadIdx.x;
  if (i >= n8) return;
  const float* src = blockIdx.y==0 ? q : (blockIdx.y==1 ? k : v);
  unsigned short* dst = blockIdx.y==0 ? qb : (blockIdx.y==1 ? kb : vb);
  const flt4* s = (const flt4*)src;
  flt4 a = s[2*i], b = s[2*i+1];
  u16x8 o;
  o[0]=f2bf(a.x); o[1]=f2bf(a.y); o[2]=f2bf(a.z); o[3]=f2bf(a.w);
  o[4]=f2bf(b.x); o[5]=f2bf(b.y); o[6]=f2bf(b.z); o[7]=f2bf(b.w);
  ((u16x8*)dst)[i] = o;
}

// ---------------- all 4 weight transposes in one launch: W[K][N] fp32 -> WT[N][K] bf16 ----------------
__global__ void wtrans_all(const float* __restrict__ Wq, const float* __restrict__ Wk,
                           const float* __restrict__ Wv, const float* __restrict__ Wo,
                           unsigned short* __restrict__ WqT, unsigned short* __restrict__ WkT,
                           unsigned short* __restrict__ WvT, unsigned short* __restrict__ WoT){
  __shared__ float tile[64][65];
  const int K = 2048;
  int id = blockIdx.x;
  const float* W; unsigned short* WT; int N, tt;
  if (id < 1024)      { W=Wq; WT=WqT; N=2048; tt=id; }
  else if (id < 1280) { W=Wk; WT=WkT; N=512;  tt=id-1024; }
  else if (id < 1536) { W=Wv; WT=WvT; N=512;  tt=id-1280; }
  else                { W=Wo; WT=WoT; N=2048; tt=id-1536; }
  int sh = (N==2048) ? 5 : 3;
  int n0 = (tt & ((1<<sh)-1))*64, k0 = (tt >> sh)*64;
  int t = threadIdx.x;
  int r = t>>4, c4 = (t&15)*4;
  #pragma unroll
  for (int i=0;i<4;i++){
    flt4 v = *(const flt4*)&W[(size_t)(k0 + r + i*16)*N + n0 + c4];
    tile[r+i*16][c4+0]=v.x; tile[r+i*16][c4+1]=v.y; tile[r+i*16][c4+2]=v.z; tile[r+i*16][c4+3]=v.w;
  }
  __syncthreads();
  #pragma unroll
  for (int i=0;i<4;i++){
    int rn = r + i*16;
    u16x4 o;
    o[0]=f2bf(tile[c4+0][rn]); o[1]=f2bf(tile[c4+1][rn]);
    o[2]=f2bf(tile[c4+2][rn]); o[3]=f2bf(tile[c4+3][rn]);
    *(u16x4*)&WT[(size_t)(n0+rn)*K + k0 + c4] = o;
  }
}

// ================= shared 64x64 GEMM K-step (XOR-swizzled LDS, 2-way banks) =================
#define GEMM64_KSTEP(A_, BT_, K_)                                              \
    __syncthreads();                                                           \
    _Pragma("unroll")                                                          \
    for (int j=0;j<2;j++){                                                     \
      int cid = (j*4+w)*64 + l;                                                \
      int row = cid>>3, sl = cid&7;                                            \
      int gsl = sl ^ (row&7);                                                  \
      gload16(&A_ [(size_t)(m0+row)*K_ + k0 + gsl*8], &As[(j*4+w)*512]);       \
      gload16(&BT_[(size_t)(n0+row)*K_ + k0 + gsl*8], &Bs[(j*4+w)*512]);       \
    }                                                                          \
    __syncthreads();                                                           \
    _Pragma("unroll")                                                          \
    for (int kk=0;kk<2;kk++){                                                  \
      bf16x8 af[2], bfv[2];                                                    \
      _Pragma("unroll")                                                        \
      for (int mt=0;mt<2;mt++){                                                \
        int row = wr+mt*16+lq;                                                 \
        af[mt] = *(const bf16x8*)&As[row*64 + (((kk*4+lg)^(lq&7))*8)];         \
      }                                                                        \
      _Pragma("unroll")                                                        \
      for (int nt=0;nt<2;nt++){                                                \
        int row = wc+nt*16+lq;                                                 \
        bfv[nt] = *(const bf16x8*)&Bs[row*64 + (((kk*4+lg)^(lq&7))*8)];        \
      }                                                                        \
      _Pragma("unroll")                                                        \
      for (int mt=0;mt<2;mt++)                                                 \
        _Pragma("unroll")                                                      \
        for (int nt=0;nt<2;nt++)                                               \
          acc[mt][nt] = __builtin_amdgcn_mfma_f32_16x16x32_bf16(af[mt], bfv[nt], acc[mt][nt], 0,0,0); \
    }

// ---------------- fused Q,K,V projections: 1536 WGs, 64x64 tiles ----------------
__global__ __launch_bounds__(256) void qkv64(const unsigned short* __restrict__ qbf,
    const unsigned short* __restrict__ kbf, const unsigned short* __restrict__ vbf,
    const unsigned short* __restrict__ WqT, const unsigned short* __restrict__ WkT,
    const unsigned short* __restrict__ WvT,
    const float* __restrict__ bq, const float* __restrict__ bk, const float* __restrict__ bv,
    unsigned short* __restrict__ Qp, unsigned short* __restrict__ Kp, unsigned short* __restrict__ VTb){
  __shared__ unsigned short As[64*64];
  __shared__ unsigned short Bs[64*64];
  const int K = 2048;
  int id = blockIdx.x;
  const unsigned short *A, *BT; const float* bias; int N, op, tt;
  if (id < 1024)      { op=0; A=qbf; BT=WqT; bias=bq; N=2048; tt=id; }
  else if (id < 1280) { op=1; A=kbf; BT=WkT; bias=bk; N=512;  tt=id-1024; }
  else                { op=2; A=vbf; BT=WvT; bias=bv; N=512;  tt=id-1280; }
  int sh = (N==2048) ? 5 : 3;
  int n0 = (tt & ((1<<sh)-1))*64, m0 = (tt >> sh)*64;
  int t = threadIdx.x, w = t>>6, l = t&63;
  int lq = l&15, lg = l>>4;
  int wr = (w>>1)*32, wc = (w&1)*32;
  f32x4 acc[2][2] = {};
  for (int k0=0;k0<K;k0+=64){
    GEMM64_KSTEP(A, BT, K)
  }
  #pragma unroll
  for (int nt=0;nt<2;nt++){
    int col = n0 + wc + nt*16 + lq;
    float bvl = bias[col];
    #pragma unroll
    for (int mt=0;mt<2;mt++){
      #pragma unroll
      for (int r=0;r<4;r++){
        int row = m0 + wr + mt*16 + lg*4 + r;
        float v = acc[mt][nt][r] + bvl;
        if (op==0)      Qp[(size_t)row*2048 + col] = f2bf(v);
        else if (op==1) Kp[(size_t)row*512 + col] = f2bf(v);
        else {
          int b = row>>10, s = row&1023;
          VTb[((size_t)(b*512 + col)<<10) + s] = f2bf(v);
        }
      }
    }
  }
}

// ---------------- O projection: 1024 WGs, 64x64 tiles, fp32 out ----------------
__global__ __launch_bounds__(256) void oproj64(const unsigned short* __restrict__ A,
    const unsigned short* __restrict__ BT, const float* __restrict__ bias,
    float* __restrict__ Cout){
  __shared__ unsigned short As[64*64];
  __shared__ unsigned short Bs[64*64];
  const int K = 2048, N = 2048;
  int n0 = blockIdx.x*64, m0 = blockIdx.y*64;
  int t = threadIdx.x, w = t>>6, l = t&63;
  int lq = l&15, lg = l>>4;
  int wr = (w>>1)*32, wc = (w&1)*32;
  f32x4 acc[2][2] = {};
  for (int k0=0;k0<K;k0+=64){
    GEMM64_KSTEP(A, BT, K)
  }
  #pragma unroll
  for (int nt=0;nt<2;nt++){
    int col = n0 + wc + nt*16 + lq;
    float bvl = bias[col];
    #pragma unroll
    for (int mt=0;mt<2;mt++){
      #pragma unroll
      for (int r=0;r<4;r++){
        int row = m0 + wr + mt*16 + lg*4 + r;
        Cout[(size_t)row*N + col] = acc[mt][nt][r] + bvl;
      }
    }
  }
}

// ---------------- fused flash attention: counted-vmcnt pipeline (T3/T4) ----------------
// Two raw s_barriers per tile; stage(kt+1)+raw(kt+2) stay IN FLIGHT across them
// (vmcnt(20) waits only for stage(kt)). Issue order pinned by sched_barrier(0)
// because the static vmcnt counts depend on it.
__global__ __launch_bounds__(256,3) void attn_k(const unsigned short* __restrict__ Q,
    const unsigned short* __restrict__ Kp, const unsigned short* __restrict__ VT,
    const float* __restrict__ pbias, const float* __restrict__ mask,
    unsigned short* __restrict__ Oout){
  __shared__ unsigned short Ks[2][4096];
  __shared__ unsigned short VTs[2][4096];
  __shared__ unsigned short Pb[4][1024];   // wave-private, XOR-swizzled [16 q][64 key]
  int t=threadIdx.x, w=t>>6, l=t&63;
  int qt=blockIdx.x, h=blockIdx.y, b=blockIdx.z;
  int kv=h>>2;
  int lq = l&15, lg = l>>4;
  int q0 = qt*64 + w*16;
  bf16x8 qf0, qf1;
  {
    const unsigned short* qp = &Q[((size_t)(b*1024 + q0 + lq))*2048 + h*64 + lg*8];
    qf0 = *(const bf16x8*)qp;
    qf1 = *(const bf16x8*)(qp + 32);
  }
  const float* pbase = &pbias[((size_t)h*1024 + (q0+lq))*1024];
  const float* mbase = &mask [((size_t)b*1024 + (q0+lq))*1024];
  f32x4 oacc[4] = {};
  float psum = 0.f;
  const float L2E   = 1.4426950408889634f;
  const float SCL2E = 0.125f*1.4426950408889634f;
  const float NFM   = -16.0f*1.4426950408889634f;  // -FIXM*L2E (fixed softmax max = 16)
  unsigned short* pw = &Pb[w][0];
  int swz = (lq&7)<<3;

  flt4 rpA[4], rmA[4], rpB[4], rmB[4], comb[4];

#define SB __builtin_amdgcn_sched_barrier(0)

#define ATTN_STAGE(buf_, kt_)                                                          \
  _Pragma("unroll")                                                                    \
  for (int j=0;j<2;j++){                                                               \
    int cid = (j*4+w)*64 + l;                                                          \
    int row = cid>>3, sl = cid&7;                                                      \
    int gsl = sl ^ (row&7);                                                            \
    gload16(&Kp[((size_t)(b*1024 + (kt_)*64 + row))*512 + kv*64 + gsl*8], &Ks[buf_][(j*4+w)*512]);          \
    gload16(&VT[((size_t)(b*512 + kv*64 + row))*1024 + (size_t)((kt_)*64 + gsl*8)], &VTs[buf_][(j*4+w)*512]);\
  }

#define ATTN_RAW(RP_, RM_, kt_)                                                        \
  _Pragma("unroll")                                                                    \
  for (int nt=0;nt<4;nt++){                                                            \
    RP_[nt] = *(const flt4*)&pbase[(kt_)*64 + nt*16 + lg*4];                           \
    RM_[nt] = *(const flt4*)&mbase[(kt_)*64 + nt*16 + lg*4];                           \
  }

#define ATTN_COMBINE(RP_, RM_)                                                         \
  _Pragma("unroll")                                                                    \
  for (int nt=0;nt<4;nt++)                                                             \
    _Pragma("unroll")                                                                  \
    for (int r=0;r<4;r++)                                                              \
      comb[nt][r] = fmaf(RP_[nt][r], SCL2E, fmaf(RM_[nt][r], L2E, NFM));

#define ATTN_COMPUTE(P_)                                                               \
  {                                                                                    \
    f32x4 sacc[4] = {};                                                                \
    __builtin_amdgcn_s_setprio(1);                                                     \
    _Pragma("unroll")                                                                  \
    for (int nt=0;nt<4;nt++){                                                          \
      int row = nt*16 + lq;                                                            \
      bf16x8 kf0 = *(const bf16x8*)&Ks[P_][row*64 + (( lg    ^ (row&7))*8)];           \
      bf16x8 kf1 = *(const bf16x8*)&Ks[P_][row*64 + (((4+lg) ^ (row&7))*8)];           \
      sacc[nt] = __builtin_amdgcn_mfma_f32_16x16x32_bf16(kf0, qf0, sacc[nt], 0,0,0);   \
      sacc[nt] = __builtin_amdgcn_mfma_f32_16x16x32_bf16(kf1, qf1, sacc[nt], 0,0,0);   \
    }                                                                                  \
    __builtin_amdgcn_s_setprio(0);                                                     \
    _Pragma("unroll")                                                                  \
    for (int nt=0;nt<4;nt++){                                                          \
      float p0 = fexp2(fmaf(sacc[nt][0], SCL2E, comb[nt][0]));                         \
      float p1 = fexp2(fmaf(sacc[nt][1], SCL2E, comb[nt][1]));                         \
      float p2 = fexp2(fmaf(sacc[nt][2], SCL2E, comb[nt][2]));                         \
      float p3 = fexp2(fmaf(sacc[nt][3], SCL2E, comb[nt][3]));                         \
      psum += (p0+p1)+(p2+p3);                                                         \
      uint2 pk;                                                                        \
      pk.x = cvt_pk_bf16(p0,p1);                                                       \
      pk.y = cvt_pk_bf16(p2,p3);                                                       \
      *(uint2*)&pw[lq*64 + ((nt*16 + lg*4) ^ swz)] = pk;                               \
    }                                                                                  \
    _Pragma("unroll")                                                                  \
    for (int kk=0;kk<2;kk++){                                                          \
      bf16x8 pa = *(const bf16x8*)&pw[lq*64 + ((kk*32 + lg*8) ^ swz)];                 \
      __builtin_amdgcn_s_setprio(1);                                                   \
      _Pragma("unroll")                                                                \
      for (int nt=0;nt<4;nt++){                                                        \
        int vrow = nt*16 + lq;                                                         \
        bf16x8 vf = *(const bf16x8*)&VTs[P_][vrow*64 + (((kk*4+lg) ^ (vrow&7))*8)];    \
        oacc[nt] = __builtin_amdgcn_mfma_f32_16x16x32_bf16(pa, vf, oacc[nt], 0,0,0);   \
      }                                                                                \
      __builtin_amdgcn_s_setprio(0);                                                   \
    }                                                                                  \
  }

// one pipelined tile: combine(kt) -> stage(kt+1) -> raw(kt+2) -> vmcnt(20),B1 -> compute -> B2
#define HALF_ITER(kt_, P_, RP_, RM_)                                                   \
  {                                                                                    \
    ATTN_COMBINE(RP_, RM_); SB;                                                        \
    ATTN_STAGE((P_)^1, (kt_)+1); SB;                                                   \
    ATTN_RAW(RP_, RM_, (kt_)+2); SB;                                                   \
    asm volatile("s_waitcnt vmcnt(20)" ::: "memory");                                  \
    __builtin_amdgcn_s_barrier(); SB;                                                  \
    ATTN_COMPUTE(P_); SB;                                                              \
    __builtin_amdgcn_s_barrier();                                                      \
  }

  // prologue (issue order matters for vmcnt counts): raw(0), stage(0), raw(1)
  ATTN_RAW(rpA, rmA, 0); SB;
  ATTN_STAGE(0, 0); SB;
  ATTN_RAW(rpB, rmB, 1); SB;

  for (int kb=0; kb<14; kb+=2){
    HALF_ITER(kb+0, 0, rpA, rmA)
    HALF_ITER(kb+1, 1, rpB, rmB)
  }
  // kt=14 (buf0, set A): stage(15), no raw
  {
    ATTN_COMBINE(rpA, rmA); SB;
    ATTN_STAGE(1, 15); SB;
    asm volatile("s_waitcnt vmcnt(12)" ::: "memory");
    __builtin_amdgcn_s_barrier(); SB;
    ATTN_COMPUTE(0); SB;
    __builtin_amdgcn_s_barrier();
  }
  // kt=15 (buf1, set B): nothing left to issue
  {
    ATTN_COMBINE(rpB, rmB); SB;
    asm volatile("s_waitcnt vmcnt(0)" ::: "memory");
    __builtin_amdgcn_s_barrier(); SB;
    ATTN_COMPUTE(1);
  }

  // finalize: reduce denominator across lg-groups, divide, store
  float lsum = psum;
  lsum += __shfl_xor(lsum, 16);
  lsum += __shfl_xor(lsum, 32);
  #pragma unroll
  for (int r=0;r<4;r++){
    float lr = __shfl(lsum, lg*4 + r);
    float linv = 1.f/lr;
    int qrow = q0 + lg*4 + r;
    #pragma unroll
    for (int nt=0;nt<4;nt++){
      Oout[((size_t)(b*1024 + qrow))*2048 + h*64 + nt*16 + lq] = f2bf(oacc[nt][r]*linv);
    }
  }
#undef HALF_ITER
#undef ATTN_COMPUTE
#undef ATTN_COMBINE
#undef ATTN_RAW
#undef ATTN_STAGE
#undef SB
}

extern "C" void kernel_launch(void* const* d_in, const int* in_sizes, int n_in,
                              void* d_out, int out_size, void* d_ws, size_t ws_size,
                              hipStream_t stream){
  (void)in_sizes; (void)n_in; (void)out_size; (void)ws_size;
  const float* query = (const float*)d_in[0];
  const float* key   = (const float*)d_in[1];
  const float* value = (const float*)d_in[2];
  const float* mask  = (const float*)d_in[3];
  const float* pbias = (const float*)d_in[4];
  const float* Wq = (const float*)d_in[5];
  const float* bq = (const float*)d_in[6];
  const float* Wk = (const float*)d_in[7];
  const float* bk = (const float*)d_in[8];
  const float* Wv = (const float*)d_in[9];
  const float* bv = (const float*)d_in[10];
  const float* Wo = (const float*)d_in[11];
  const float* bo = (const float*)d_in[12];
  char* ws = (char*)d_ws;
  const size_t MB = (size_t)1<<20;
  unsigned short* qbf = (unsigned short*)(ws + 0*MB);
  unsigned short* kbf = (unsigned short*)(ws + 8*MB);
  unsigned short* vbf = (unsigned short*)(ws + 16*MB);
  unsigned short* WqT = (unsigned short*)(ws + 24*MB);
  unsigned short* WkT = (unsigned short*)(ws + 32*MB);
  unsigned short* WvT = (unsigned short*)(ws + 34*MB);
  unsigned short* WoT = (unsigned short*)(ws + 36*MB);
  unsigned short* Qp  = (unsigned short*)(ws + 44*MB);
  unsigned short* Kp  = (unsigned short*)(ws + 52*MB);
  unsigned short* VTb = (unsigned short*)(ws + 54*MB);
  unsigned short* Aout= (unsigned short*)(ws + 56*MB);

  cvt3_k<<<dim3(2048,3),256,0,stream>>>(query, key, value, qbf, kbf, vbf, 524288);
  wtrans_all<<<2560,256,0,stream>>>(Wq, Wk, Wv, Wo, WqT, WkT, WvT, WoT);
  qkv64<<<1536,256,0,stream>>>(qbf, kbf, vbf, WqT, WkT, WvT, bq, bk, bv, Qp, Kp, VTb);
  attn_k<<<dim3(16,32,2),256,0,stream>>>(Qp, Kp, VTb, pbias, mask, Aout);
  oproj64<<<dim3(32,32),256,0,stream>>>(Aout, WoT, bo, (float*)d_out);
}

// Round 7
// 183.290 us; speedup vs baseline: 1.0765x; 1.0765x over previous
//
#include <hip/hip_runtime.h>
#include <stdint.h>

#define DEVI __device__ __forceinline__

typedef __attribute__((ext_vector_type(8))) short bf16x8;
typedef __attribute__((ext_vector_type(4))) float f32x4;
typedef __attribute__((ext_vector_type(4))) float flt4;
typedef __attribute__((ext_vector_type(8))) unsigned short u16x8;
typedef __attribute__((ext_vector_type(4))) unsigned short u16x4;

DEVI unsigned short f2bf(float f){
  union{float f;uint32_t u;}v; v.f=f;
  uint32_t u=v.u;
  u += 0x7FFFu + ((u>>16)&1u);
  return (unsigned short)(u>>16);
}

DEVI uint32_t cvt_pk_bf16(float lo, float hi){
  uint32_t r;
  asm("v_cvt_pk_bf16_f32 %0, %1, %2" : "=v"(r) : "v"(lo), "v"(hi));
  return r;
}

DEVI float fexp2(float x){
#if __has_builtin(__builtin_amdgcn_exp2f)
  return __builtin_amdgcn_exp2f(x);
#else
  return exp2f(x);
#endif
}

DEVI void gload16(const void* g, void* l){
  __builtin_amdgcn_global_load_lds((const __attribute__((address_space(1))) void*)g,
                                   (__attribute__((address_space(3))) void*)l, 16, 0, 0);
}

// ---------------- fp32 -> bf16 convert, z-batched over {q,k,v} ----------------
__global__ void cvt3_k(const float* __restrict__ q, const float* __restrict__ k,
                       const float* __restrict__ v, unsigned short* __restrict__ qb,
                       unsigned short* __restrict__ kb, unsigned short* __restrict__ vb, int n8){
  int i = blockIdx.x*256 + threadIdx.x;
  if (i >= n8) return;
  const float* src = blockIdx.y==0 ? q : (blockIdx.y==1 ? k : v);
  unsigned short* dst = blockIdx.y==0 ? qb : (blockIdx.y==1 ? kb : vb);
  const flt4* s = (const flt4*)src;
  flt4 a = s[2*i], b = s[2*i+1];
  u16x8 o;
  o[0]=f2bf(a.x); o[1]=f2bf(a.y); o[2]=f2bf(a.z); o[3]=f2bf(a.w);
  o[4]=f2bf(b.x); o[5]=f2bf(b.y); o[6]=f2bf(b.z); o[7]=f2bf(b.w);
  ((u16x8*)dst)[i] = o;
}

// ---------------- all 4 weight transposes in one launch: W[K][N] fp32 -> WT[N][K] bf16 ----------------
__global__ void wtrans_all(const float* __restrict__ Wq, const float* __restrict__ Wk,
                           const float* __restrict__ Wv, const float* __restrict__ Wo,
                           unsigned short* __restrict__ WqT, unsigned short* __restrict__ WkT,
                           unsigned short* __restrict__ WvT, unsigned short* __restrict__ WoT){
  __shared__ float tile[64][65];
  const int K = 2048;
  int id = blockIdx.x;
  const float* W; unsigned short* WT; int N, tt;
  if (id < 1024)      { W=Wq; WT=WqT; N=2048; tt=id; }
  else if (id < 1280) { W=Wk; WT=WkT; N=512;  tt=id-1024; }
  else if (id < 1536) { W=Wv; WT=WvT; N=512;  tt=id-1280; }
  else                { W=Wo; WT=WoT; N=2048; tt=id-1536; }
  int sh = (N==2048) ? 5 : 3;
  int n0 = (tt & ((1<<sh)-1))*64, k0 = (tt >> sh)*64;
  int t = threadIdx.x;
  int r = t>>4, c4 = (t&15)*4;
  #pragma unroll
  for (int i=0;i<4;i++){
    flt4 v = *(const flt4*)&W[(size_t)(k0 + r + i*16)*N + n0 + c4];
    tile[r+i*16][c4+0]=v.x; tile[r+i*16][c4+1]=v.y; tile[r+i*16][c4+2]=v.z; tile[r+i*16][c4+3]=v.w;
  }
  __syncthreads();
  #pragma unroll
  for (int i=0;i<4;i++){
    int rn = r + i*16;
    u16x4 o;
    o[0]=f2bf(tile[c4+0][rn]); o[1]=f2bf(tile[c4+1][rn]);
    o[2]=f2bf(tile[c4+2][rn]); o[3]=f2bf(tile[c4+3][rn]);
    *(u16x4*)&WT[(size_t)(n0+rn)*K + k0 + c4] = o;
  }
}

// ================= shared 64x64 GEMM K-step (XOR-swizzled LDS, 2-way banks) =================
#define GEMM64_KSTEP(A_, BT_, K_)                                              \
    __syncthreads();                                                           \
    _Pragma("unroll")                                                          \
    for (int j=0;j<2;j++){                                                     \
      int cid = (j*4+w)*64 + l;                                                \
      int row = cid>>3, sl = cid&7;                                            \
      int gsl = sl ^ (row&7);                                                  \
      gload16(&A_ [(size_t)(m0+row)*K_ + k0 + gsl*8], &As[(j*4+w)*512]);       \
      gload16(&BT_[(size_t)(n0+row)*K_ + k0 + gsl*8], &Bs[(j*4+w)*512]);       \
    }                                                                          \
    __syncthreads();                                                           \
    _Pragma("unroll")                                                          \
    for (int kk=0;kk<2;kk++){                                                  \
      bf16x8 af[2], bfv[2];                                                    \
      _Pragma("unroll")                                                        \
      for (int mt=0;mt<2;mt++){                                                \
        int row = wr+mt*16+lq;                                                 \
        af[mt] = *(const bf16x8*)&As[row*64 + (((kk*4+lg)^(lq&7))*8)];         \
      }                                                                        \
      _Pragma("unroll")                                                        \
      for (int nt=0;nt<2;nt++){                                                \
        int row = wc+nt*16+lq;                                                 \
        bfv[nt] = *(const bf16x8*)&Bs[row*64 + (((kk*4+lg)^(lq&7))*8)];        \
      }                                                                        \
      _Pragma("unroll")                                                        \
      for (int mt=0;mt<2;mt++)                                                 \
        _Pragma("unroll")                                                      \
        for (int nt=0;nt<2;nt++)                                               \
          acc[mt][nt] = __builtin_amdgcn_mfma_f32_16x16x32_bf16(af[mt], bfv[nt], acc[mt][nt], 0,0,0); \
    }

// ---------------- fused Q,K,V projections: 1536 WGs, 64x64 tiles ----------------
__global__ __launch_bounds__(256) void qkv64(const unsigned short* __restrict__ qbf,
    const unsigned short* __restrict__ kbf, const unsigned short* __restrict__ vbf,
    const unsigned short* __restrict__ WqT, const unsigned short* __restrict__ WkT,
    const unsigned short* __restrict__ WvT,
    const float* __restrict__ bq, const float* __restrict__ bk, const float* __restrict__ bv,
    unsigned short* __restrict__ Qp, unsigned short* __restrict__ Kp, unsigned short* __restrict__ VTb){
  __shared__ unsigned short As[64*64];
  __shared__ unsigned short Bs[64*64];
  const int K = 2048;
  int id = blockIdx.x;
  const unsigned short *A, *BT; const float* bias; int N, op, tt;
  if (id < 1024)      { op=0; A=qbf; BT=WqT; bias=bq; N=2048; tt=id; }
  else if (id < 1280) { op=1; A=kbf; BT=WkT; bias=bk; N=512;  tt=id-1024; }
  else                { op=2; A=vbf; BT=WvT; bias=bv; N=512;  tt=id-1280; }
  int sh = (N==2048) ? 5 : 3;
  int n0 = (tt & ((1<<sh)-1))*64, m0 = (tt >> sh)*64;
  int t = threadIdx.x, w = t>>6, l = t&63;
  int lq = l&15, lg = l>>4;
  int wr = (w>>1)*32, wc = (w&1)*32;
  f32x4 acc[2][2] = {};
  for (int k0=0;k0<K;k0+=64){
    GEMM64_KSTEP(A, BT, K)
  }
  #pragma unroll
  for (int nt=0;nt<2;nt++){
    int col = n0 + wc + nt*16 + lq;
    float bvl = bias[col];
    #pragma unroll
    for (int mt=0;mt<2;mt++){
      #pragma unroll
      for (int r=0;r<4;r++){
        int row = m0 + wr + mt*16 + lg*4 + r;
        float v = acc[mt][nt][r] + bvl;
        if (op==0)      Qp[(size_t)row*2048 + col] = f2bf(v);
        else if (op==1) Kp[(size_t)row*512 + col] = f2bf(v);
        else {
          int b = row>>10, s = row&1023;
          VTb[((size_t)(b*512 + col)<<10) + s] = f2bf(v);
        }
      }
    }
  }
}

// ---------------- O projection: 1024 WGs, 64x64 tiles, fp32 out ----------------
__global__ __launch_bounds__(256) void oproj64(const unsigned short* __restrict__ A,
    const unsigned short* __restrict__ BT, const float* __restrict__ bias,
    float* __restrict__ Cout){
  __shared__ unsigned short As[64*64];
  __shared__ unsigned short Bs[64*64];
  const int K = 2048, N = 2048;
  int n0 = blockIdx.x*64, m0 = blockIdx.y*64;
  int t = threadIdx.x, w = t>>6, l = t&63;
  int lq = l&15, lg = l>>4;
  int wr = (w>>1)*32, wc = (w&1)*32;
  f32x4 acc[2][2] = {};
  for (int k0=0;k0<K;k0+=64){
    GEMM64_KSTEP(A, BT, K)
  }
  #pragma unroll
  for (int nt=0;nt<2;nt++){
    int col = n0 + wc + nt*16 + lq;
    float bvl = bias[col];
    #pragma unroll
    for (int mt=0;mt<2;mt++){
      #pragma unroll
      for (int r=0;r<4;r++){
        int row = m0 + wr + mt*16 + lg*4 + r;
        Cout[(size_t)row*N + col] = acc[mt][nt][r] + bvl;
      }
    }
  }
}

// ---------------- fused flash attention: counted-vmcnt pipeline, round-5 register budget ----------------
// Per tile: COMBINE(kt) -> STAGE(kt+1) [4 gload_lds] -> RAW(kt+1) [8 dwordx4]
//           -> COMPUTE(kt) -> s_waitcnt vmcnt(8) + raw s_barrier.
// vmcnt(8) waits only the 4 stage loads; the 8 bias/mask loads stay in flight
// across the barrier and are auto-waited by the compiler at next COMBINE.
__global__ __launch_bounds__(256,4) void attn_k(const unsigned short* __restrict__ Q,
    const unsigned short* __restrict__ Kp, const unsigned short* __restrict__ VT,
    const float* __restrict__ pbias, const float* __restrict__ mask,
    unsigned short* __restrict__ Oout){
  __shared__ unsigned short Ks[2][4096];
  __shared__ unsigned short VTs[2][4096];
  __shared__ unsigned short Pb[4][1024];   // wave-private, XOR-swizzled [16 q][64 key]
  int t=threadIdx.x, w=t>>6, l=t&63;
  int qt=blockIdx.x, h=blockIdx.y, b=blockIdx.z;
  int kv=h>>2;
  int lq = l&15, lg = l>>4;
  int q0 = qt*64 + w*16;
  bf16x8 qf0, qf1;
  {
    const unsigned short* qp = &Q[((size_t)(b*1024 + q0 + lq))*2048 + h*64 + lg*8];
    qf0 = *(const bf16x8*)qp;
    qf1 = *(const bf16x8*)(qp + 32);
  }
  const float* pbase = &pbias[((size_t)h*1024 + (q0+lq))*1024];
  const float* mbase = &mask [((size_t)b*1024 + (q0+lq))*1024];
  f32x4 oacc[4] = {};
  float psum = 0.f;
  const float L2E   = 1.4426950408889634f;
  const float SCL2E = 0.125f*1.4426950408889634f;
  const float NFM   = -16.0f*1.4426950408889634f;  // -FIXM*L2E (fixed softmax max = 16)
  unsigned short* pw = &Pb[w][0];
  int swz = (lq&7)<<3;

  flt4 praw[4], mraw[4], comb[4];

#define ATTN_STAGE(buf_, kt_)                                                          \
  _Pragma("unroll")                                                                    \
  for (int j=0;j<2;j++){                                                               \
    int cid = (j*4+w)*64 + l;                                                          \
    int row = cid>>3, sl = cid&7;                                                      \
    int gsl = sl ^ (row&7);                                                            \
    gload16(&Kp[((size_t)(b*1024 + (kt_)*64 + row))*512 + kv*64 + gsl*8], &Ks[buf_][(j*4+w)*512]);          \
    gload16(&VT[((size_t)(b*512 + kv*64 + row))*1024 + (size_t)((kt_)*64 + gsl*8)], &VTs[buf_][(j*4+w)*512]);\
  }

#define ATTN_RAW(kt_)                                                                  \
  _Pragma("unroll")                                                                    \
  for (int nt=0;nt<4;nt++){                                                            \
    praw[nt] = *(const flt4*)&pbase[(kt_)*64 + nt*16 + lg*4];                          \
    mraw[nt] = *(const flt4*)&mbase[(kt_)*64 + nt*16 + lg*4];                          \
  }

#define ATTN_COMBINE()                                                                 \
  _Pragma("unroll")                                                                    \
  for (int nt=0;nt<4;nt++)                                                             \
    _Pragma("unroll")                                                                  \
    for (int r=0;r<4;r++)                                                              \
      comb[nt][r] = fmaf(praw[nt][r], 0.125f, mraw[nt][r] - 16.0f)*L2E;

#define ATTN_COMPUTE(P_)                                                               \
  {                                                                                    \
    f32x4 sacc[4] = {};                                                                \
    __builtin_amdgcn_s_setprio(1);                                                     \
    _Pragma("unroll")                                                                  \
    for (int nt=0;nt<4;nt++){                                                          \
      int row = nt*16 + lq;                                                            \
      bf16x8 kf0 = *(const bf16x8*)&Ks[P_][row*64 + (( lg    ^ (row&7))*8)];           \
      bf16x8 kf1 = *(const bf16x8*)&Ks[P_][row*64 + (((4+lg) ^ (row&7))*8)];           \
      sacc[nt] = __builtin_amdgcn_mfma_f32_16x16x32_bf16(kf0, qf0, sacc[nt], 0,0,0);   \
      sacc[nt] = __builtin_amdgcn_mfma_f32_16x16x32_bf16(kf1, qf1, sacc[nt], 0,0,0);   \
    }                                                                                  \
    __builtin_amdgcn_s_setprio(0);                                                     \
    _Pragma("unroll")                                                                  \
    for (int nt=0;nt<4;nt++){                                                          \
      float p0 = fexp2(fmaf(sacc[nt][0], SCL2E, comb[nt][0]));                         \
      float p1 = fexp2(fmaf(sacc[nt][1], SCL2E, comb[nt][1]));                         \
      float p2 = fexp2(fmaf(sacc[nt][2], SCL2E, comb[nt][2]));                         \
      float p3 = fexp2(fmaf(sacc[nt][3], SCL2E, comb[nt][3]));                         \
      psum += (p0+p1)+(p2+p3);                                                         \
      uint2 pk;                                                                        \
      pk.x = cvt_pk_bf16(p0,p1);                                                       \
      pk.y = cvt_pk_bf16(p2,p3);                                                       \
      *(uint2*)&pw[lq*64 + ((nt*16 + lg*4) ^ swz)] = pk;                               \
    }                                                                                  \
    _Pragma("unroll")                                                                  \
    for (int kk=0;kk<2;kk++){                                                          \
      bf16x8 pa = *(const bf16x8*)&pw[lq*64 + ((kk*32 + lg*8) ^ swz)];                 \
      __builtin_amdgcn_s_setprio(1);                                                   \
      _Pragma("unroll")                                                                \
      for (int nt=0;nt<4;nt++){                                                        \
        int vrow = nt*16 + lq;                                                         \
        bf16x8 vf = *(const bf16x8*)&VTs[P_][vrow*64 + (((kk*4+lg) ^ (vrow&7))*8)];    \
        oacc[nt] = __builtin_amdgcn_mfma_f32_16x16x32_bf16(pa, vf, oacc[nt], 0,0,0);   \
      }                                                                                \
      __builtin_amdgcn_s_setprio(0);                                                   \
    }                                                                                  \
  }

  // prologue: stage tile 0, raw tile 0; wait stage (8 raws outstanding) + barrier
  ATTN_STAGE(0, 0)
  ATTN_RAW(0)
  asm volatile("s_waitcnt vmcnt(8)" ::: "memory");
  __builtin_amdgcn_s_barrier();

  for (int kt=0; kt<16; ++kt){
    int cur = kt&1;
    ATTN_COMBINE()                   // consumes praw/mraw(kt); compiler auto-waits
    if (kt < 15){
      ATTN_STAGE(cur^1, kt+1)        // 4 gload_lds
      ATTN_RAW(kt+1)                 // 8 dwordx4, stay in flight across barrier
    }
    ATTN_COMPUTE(cur)
    if (kt < 15){
      asm volatile("s_waitcnt vmcnt(8)" ::: "memory");  // stage(kt+1) done; raws in flight
      __builtin_amdgcn_s_barrier();
    }
  }

  // finalize: reduce denominator across lg-groups, divide, store
  float lsum = psum;
  lsum += __shfl_xor(lsum, 16);
  lsum += __shfl_xor(lsum, 32);
  #pragma unroll
  for (int r=0;r<4;r++){
    float lr = __shfl(lsum, lg*4 + r);
    float linv = 1.f/lr;
    int qrow = q0 + lg*4 + r;
    #pragma unroll
    for (int nt=0;nt<4;nt++){
      Oout[((size_t)(b*1024 + qrow))*2048 + h*64 + nt*16 + lq] = f2bf(oacc[nt][r]*linv);
    }
  }
#undef ATTN_COMPUTE
#undef ATTN_COMBINE
#undef ATTN_RAW
#undef ATTN_STAGE
}

extern "C" void kernel_launch(void* const* d_in, const int* in_sizes, int n_in,
                              void* d_out, int out_size, void* d_ws, size_t ws_size,
                              hipStream_t stream){
  (void)in_sizes; (void)n_in; (void)out_size; (void)ws_size;
  const float* query = (const float*)d_in[0];
  const float* key   = (const float*)d_in[1];
  const float* value = (const float*)d_in[2];
  const float* mask  = (const float*)d_in[3];
  const float* pbias = (const float*)d_in[4];
  const float* Wq = (const float*)d_in[5];
  const float* bq = (const float*)d_in[6];
  const float* Wk = (const float*)d_in[7];
  const float* bk = (const float*)d_in[8];
  const float* Wv = (const float*)d_in[9];
  const float* bv = (const float*)d_in[10];
  const float* Wo = (const float*)d_in[11];
  const float* bo = (const float*)d_in[12];
  char* ws = (char*)d_ws;
  const size_t MB = (size_t)1<<20;
  unsigned short* qbf = (unsigned short*)(ws + 0*MB);
  unsigned short* kbf = (unsigned short*)(ws + 8*MB);
  unsigned short* vbf = (unsigned short*)(ws + 16*MB);
  unsigned short* WqT = (unsigned short*)(ws + 24*MB);
  unsigned short* WkT = (unsigned short*)(ws + 32*MB);
  unsigned short* WvT = (unsigned short*)(ws + 34*MB);
  unsigned short* WoT = (unsigned short*)(ws + 36*MB);
  unsigned short* Qp  = (unsigned short*)(ws + 44*MB);
  unsigned short* Kp  = (unsigned short*)(ws + 52*MB);
  unsigned short* VTb = (unsigned short*)(ws + 54*MB);
  unsigned short* Aout= (unsigned short*)(ws + 56*MB);

  cvt3_k<<<dim3(2048,3),256,0,stream>>>(query, key, value, qbf, kbf, vbf, 524288);
  wtrans_all<<<2560,256,0,stream>>>(Wq, Wk, Wv, Wo, WqT, WkT, WvT, WoT);
  qkv64<<<1536,256,0,stream>>>(qbf, kbf, vbf, WqT, WkT, WvT, bq, bk, bv, Qp, Kp, VTb);
  attn_k<<<dim3(16,32,2),256,0,stream>>>(Qp, Kp, VTb, pbias, mask, Aout);
  oproj64<<<dim3(32,32),256,0,stream>>>(Aout, WoT, bo, (float*)d_out);
}

// Round 8
// 153.744 us; speedup vs baseline: 1.2834x; 1.1922x over previous
//
#include <hip/hip_runtime.h>
#include <stdint.h>

#define DEVI __device__ __forceinline__

typedef __attribute__((ext_vector_type(8))) short bf16x8;
typedef __attribute__((ext_vector_type(4))) float f32x4;
typedef __attribute__((ext_vector_type(4))) float flt4;
typedef __attribute__((ext_vector_type(8))) unsigned short u16x8;
typedef __attribute__((ext_vector_type(4))) unsigned short u16x4;

DEVI unsigned short f2bf(float f){
  union{float f;uint32_t u;}v; v.f=f;
  uint32_t u=v.u;
  u += 0x7FFFu + ((u>>16)&1u);
  return (unsigned short)(u>>16);
}

DEVI uint32_t cvt_pk_bf16(float lo, float hi){
  uint32_t r;
  asm("v_cvt_pk_bf16_f32 %0, %1, %2" : "=v"(r) : "v"(lo), "v"(hi));
  return r;
}

DEVI float fexp2(float x){
#if __has_builtin(__builtin_amdgcn_exp2f)
  return __builtin_amdgcn_exp2f(x);
#else
  return exp2f(x);
#endif
}

DEVI void gload16(const void* g, void* l){
  __builtin_amdgcn_global_load_lds((const __attribute__((address_space(1))) void*)g,
                                   (__attribute__((address_space(3))) void*)l, 16, 0, 0);
}

// ---------------- fp32 -> bf16 convert, z-batched over {q,k,v} ----------------
__global__ void cvt3_k(const float* __restrict__ q, const float* __restrict__ k,
                       const float* __restrict__ v, unsigned short* __restrict__ qb,
                       unsigned short* __restrict__ kb, unsigned short* __restrict__ vb, int n8){
  int i = blockIdx.x*256 + threadIdx.x;
  if (i >= n8) return;
  const float* src = blockIdx.y==0 ? q : (blockIdx.y==1 ? k : v);
  unsigned short* dst = blockIdx.y==0 ? qb : (blockIdx.y==1 ? kb : vb);
  const flt4* s = (const flt4*)src;
  flt4 a = s[2*i], b = s[2*i+1];
  u16x8 o;
  o[0]=f2bf(a.x); o[1]=f2bf(a.y); o[2]=f2bf(a.z); o[3]=f2bf(a.w);
  o[4]=f2bf(b.x); o[5]=f2bf(b.y); o[6]=f2bf(b.z); o[7]=f2bf(b.w);
  ((u16x8*)dst)[i] = o;
}

// ---------------- all 4 weight transposes in one launch: W[K][N] fp32 -> WT[N][K] bf16 ----------------
__global__ void wtrans_all(const float* __restrict__ Wq, const float* __restrict__ Wk,
                           const float* __restrict__ Wv, const float* __restrict__ Wo,
                           unsigned short* __restrict__ WqT, unsigned short* __restrict__ WkT,
                           unsigned short* __restrict__ WvT, unsigned short* __restrict__ WoT){
  __shared__ float tile[64][65];
  const int K = 2048;
  int id = blockIdx.x;
  const float* W; unsigned short* WT; int N, tt;
  if (id < 1024)      { W=Wq; WT=WqT; N=2048; tt=id; }
  else if (id < 1280) { W=Wk; WT=WkT; N=512;  tt=id-1024; }
  else if (id < 1536) { W=Wv; WT=WvT; N=512;  tt=id-1280; }
  else                { W=Wo; WT=WoT; N=2048; tt=id-1536; }
  int sh = (N==2048) ? 5 : 3;
  int n0 = (tt & ((1<<sh)-1))*64, k0 = (tt >> sh)*64;
  int t = threadIdx.x;
  int r = t>>4, c4 = (t&15)*4;
  #pragma unroll
  for (int i=0;i<4;i++){
    flt4 v = *(const flt4*)&W[(size_t)(k0 + r + i*16)*N + n0 + c4];
    tile[r+i*16][c4+0]=v.x; tile[r+i*16][c4+1]=v.y; tile[r+i*16][c4+2]=v.z; tile[r+i*16][c4+3]=v.w;
  }
  __syncthreads();
  #pragma unroll
  for (int i=0;i<4;i++){
    int rn = r + i*16;
    u16x4 o;
    o[0]=f2bf(tile[c4+0][rn]); o[1]=f2bf(tile[c4+1][rn]);
    o[2]=f2bf(tile[c4+2][rn]); o[3]=f2bf(tile[c4+3][rn]);
    *(u16x4*)&WT[(size_t)(n0+rn)*K + k0 + c4] = o;
  }
}

// ================= shared 64x64 GEMM K-step (XOR-swizzled LDS, 2-way banks) =================
#define GEMM64_KSTEP(A_, BT_, K_)                                              \
    __syncthreads();                                                           \
    _Pragma("unroll")                                                          \
    for (int j=0;j<2;j++){                                                     \
      int cid = (j*4+w)*64 + l;                                                \
      int row = cid>>3, sl = cid&7;                                            \
      int gsl = sl ^ (row&7);                                                  \
      gload16(&A_ [(size_t)(m0+row)*K_ + k0 + gsl*8], &As[(j*4+w)*512]);       \
      gload16(&BT_[(size_t)(n0+row)*K_ + k0 + gsl*8], &Bs[(j*4+w)*512]);       \
    }                                                                          \
    __syncthreads();                                                           \
    _Pragma("unroll")                                                          \
    for (int kk=0;kk<2;kk++){                                                  \
      bf16x8 af[2], bfv[2];                                                    \
      _Pragma("unroll")                                                        \
      for (int mt=0;mt<2;mt++){                                                \
        int row = wr+mt*16+lq;                                                 \
        af[mt] = *(const bf16x8*)&As[row*64 + (((kk*4+lg)^(lq&7))*8)];         \
      }                                                                        \
      _Pragma("unroll")                                                        \
      for (int nt=0;nt<2;nt++){                                                \
        int row = wc+nt*16+lq;                                                 \
        bfv[nt] = *(const bf16x8*)&Bs[row*64 + (((kk*4+lg)^(lq&7))*8)];        \
      }                                                                        \
      _Pragma("unroll")                                                        \
      for (int mt=0;mt<2;mt++)                                                 \
        _Pragma("unroll")                                                      \
        for (int nt=0;nt<2;nt++)                                               \
          acc[mt][nt] = __builtin_amdgcn_mfma_f32_16x16x32_bf16(af[mt], bfv[nt], acc[mt][nt], 0,0,0); \
    }

// ---------------- fused Q,K,V projections: 1536 WGs, 64x64 tiles ----------------
__global__ __launch_bounds__(256) void qkv64(const unsigned short* __restrict__ qbf,
    const unsigned short* __restrict__ kbf, const unsigned short* __restrict__ vbf,
    const unsigned short* __restrict__ WqT, const unsigned short* __restrict__ WkT,
    const unsigned short* __restrict__ WvT,
    const float* __restrict__ bq, const float* __restrict__ bk, const float* __restrict__ bv,
    unsigned short* __restrict__ Qp, unsigned short* __restrict__ Kp, unsigned short* __restrict__ VTb){
  __shared__ unsigned short As[64*64];
  __shared__ unsigned short Bs[64*64];
  const int K = 2048;
  int id = blockIdx.x;
  const unsigned short *A, *BT; const float* bias; int N, op, tt;
  if (id < 1024)      { op=0; A=qbf; BT=WqT; bias=bq; N=2048; tt=id; }
  else if (id < 1280) { op=1; A=kbf; BT=WkT; bias=bk; N=512;  tt=id-1024; }
  else                { op=2; A=vbf; BT=WvT; bias=bv; N=512;  tt=id-1280; }
  int sh = (N==2048) ? 5 : 3;
  int n0 = (tt & ((1<<sh)-1))*64, m0 = (tt >> sh)*64;
  int t = threadIdx.x, w = t>>6, l = t&63;
  int lq = l&15, lg = l>>4;
  int wr = (w>>1)*32, wc = (w&1)*32;
  f32x4 acc[2][2] = {};
  for (int k0=0;k0<K;k0+=64){
    GEMM64_KSTEP(A, BT, K)
  }
  #pragma unroll
  for (int nt=0;nt<2;nt++){
    int col = n0 + wc + nt*16 + lq;
    float bvl = bias[col];
    #pragma unroll
    for (int mt=0;mt<2;mt++){
      #pragma unroll
      for (int r=0;r<4;r++){
        int row = m0 + wr + mt*16 + lg*4 + r;
        float v = acc[mt][nt][r] + bvl;
        if (op==0)      Qp[(size_t)row*2048 + col] = f2bf(v);
        else if (op==1) Kp[(size_t)row*512 + col] = f2bf(v);
        else {
          int b = row>>10, s = row&1023;
          VTb[((size_t)(b*512 + col)<<10) + s] = f2bf(v);
        }
      }
    }
  }
}

// ---------------- O projection: 1024 WGs, 64x64 tiles, fp32 out ----------------
__global__ __launch_bounds__(256) void oproj64(const unsigned short* __restrict__ A,
    const unsigned short* __restrict__ BT, const float* __restrict__ bias,
    float* __restrict__ Cout){
  __shared__ unsigned short As[64*64];
  __shared__ unsigned short Bs[64*64];
  const int K = 2048, N = 2048;
  int n0 = blockIdx.x*64, m0 = blockIdx.y*64;
  int t = threadIdx.x, w = t>>6, l = t&63;
  int lq = l&15, lg = l>>4;
  int wr = (w>>1)*32, wc = (w&1)*32;
  f32x4 acc[2][2] = {};
  for (int k0=0;k0<K;k0+=64){
    GEMM64_KSTEP(A, BT, K)
  }
  #pragma unroll
  for (int nt=0;nt<2;nt++){
    int col = n0 + wc + nt*16 + lq;
    float bvl = bias[col];
    #pragma unroll
    for (int mt=0;mt<2;mt++){
      #pragma unroll
      for (int r=0;r<4;r++){
        int row = m0 + wr + mt*16 + lg*4 + r;
        Cout[(size_t)row*N + col] = acc[mt][nt][r] + bvl;
      }
    }
  }
}

// ---------------- fused flash attention: kv-group WGs (8 waves = 4 heads x 2 q-halves) ----------------
// Byte-reduction restructure: K/V staged once per kv-group (not per head); mask staged
// to LDS once per WG (shared by 4 heads); bias per-head register prefetch 2 tiles deep.
// Q: bf16 [B*S][2048]; Kp: bf16 [B*S][512]; VT: bf16 [(b*512+kv*64+d)][1024]
// pbias: fp32 [H][S][S]; mask: fp32 [B][S][S]; Oout: bf16 [B*S][2048]
__global__ __launch_bounds__(512,4) void attn_k(const unsigned short* __restrict__ Q,
    const unsigned short* __restrict__ Kp, const unsigned short* __restrict__ VT,
    const float* __restrict__ pbias, const float* __restrict__ mask,
    unsigned short* __restrict__ Oout){
  __shared__ unsigned short Ks[2][4096];   // [key 64][d 64] bf16, row-XOR swizzled
  __shared__ unsigned short VTs[2][4096];  // [d 64][key 64] bf16, row-XOR swizzled
  __shared__ float Ms[2][2048];            // [qrow 32][key 64] fp32, chunk-XOR swizzled
  __shared__ unsigned short Pb[8][1024];   // wave-private P, XOR-swizzled
  int t=threadIdx.x, w=t>>6, l=t&63;
  // chunked XCD remap: logical-consecutive WGs (b pairs sharing pbias) land on one XCD
  int phys = blockIdx.x;
  int lin = (phys&7)*64 + (phys>>3);       // 512 = 8 x 64, bijective
  int qb = lin>>4, kv = (lin>>1)&7, b = lin&1;
  int h = kv*4 + (w&3);
  int qhalf = w>>2;
  int lq = l&15, lg = l>>4;
  int q0 = qb*32 + qhalf*16;
  int mr = qhalf*16 + lq;                  // this lane's row in the WG mask tile
  bf16x8 qf0, qf1;
  {
    const unsigned short* qp = &Q[((size_t)(b*1024 + q0 + lq))*2048 + h*64 + lg*8];
    qf0 = *(const bf16x8*)qp;
    qf1 = *(const bf16x8*)(qp + 32);
  }
  const float* pbase  = &pbias[((size_t)h*1024 + (q0+lq))*1024];
  const float* maskWG = &mask [((size_t)(b*1024 + qb*32))*1024];
  f32x4 oacc[4] = {};
  float psum = 0.f;
  const float L2E   = 1.4426950408889634f;
  const float SCL2E = 0.125f*1.4426950408889634f;
  const float NFM   = -16.0f*1.4426950408889634f;  // fixed softmax max = 16
  unsigned short* pw = &Pb[w][0];
  int swz = (lq&7)<<3;

  flt4 RA[4], RB[4], comb[4];

// stage K(8KB)+V(8KB)+mask(8KB): 1 gload_lds each per wave (8 waves cover the tiles)
#define ATTN_STAGE(buf_, kt_)                                                           \
  {                                                                                     \
    int c = w*64 + l;                                                                   \
    int krow = c>>3, ksl = (c&7)^(krow&7);                                              \
    gload16(&Kp[((size_t)(b*1024 + (kt_)*64 + krow))*512 + kv*64 + ksl*8], &Ks[buf_][w*512]);          \
    gload16(&VT[((size_t)(b*512 + kv*64 + krow))*1024 + (size_t)((kt_)*64 + ksl*8)], &VTs[buf_][w*512]);\
    int mrow = c>>4, msl = (c&15)^(mrow&7);                                             \
    gload16(&maskWG[(size_t)mrow*1024 + (kt_)*64 + msl*4], &Ms[buf_][w*256]);           \
  }

#define ATTN_RAW(RP_, kt_)                                                              \
  _Pragma("unroll")                                                                     \
  for (int nt=0;nt<4;nt++)                                                              \
    RP_[nt] = *(const flt4*)&pbase[(kt_)*64 + nt*16 + lg*4];

#define ATTN_COMBINE(RP_, cur_)                                                         \
  _Pragma("unroll")                                                                     \
  for (int nt=0;nt<4;nt++){                                                             \
    flt4 m4 = *(const flt4*)&Ms[cur_][mr*64 + (((nt*4+lg)^(mr&7))<<2)];                 \
    _Pragma("unroll")                                                                   \
    for (int r=0;r<4;r++)                                                               \
      comb[nt][r] = fmaf(RP_[nt][r], SCL2E, fmaf(m4[r], L2E, NFM));                     \
  }

#define ATTN_COMPUTE(P_)                                                                \
  {                                                                                     \
    f32x4 sacc[4] = {};                                                                 \
    __builtin_amdgcn_s_setprio(1);                                                      \
    _Pragma("unroll")                                                                   \
    for (int nt=0;nt<4;nt++){                                                           \
      int row = nt*16 + lq;                                                             \
      bf16x8 kf0 = *(const bf16x8*)&Ks[P_][row*64 + (( lg    ^ (row&7))*8)];            \
      bf16x8 kf1 = *(const bf16x8*)&Ks[P_][row*64 + (((4+lg) ^ (row&7))*8)];            \
      sacc[nt] = __builtin_amdgcn_mfma_f32_16x16x32_bf16(kf0, qf0, sacc[nt], 0,0,0);    \
      sacc[nt] = __builtin_amdgcn_mfma_f32_16x16x32_bf16(kf1, qf1, sacc[nt], 0,0,0);    \
    }                                                                                   \
    __builtin_amdgcn_s_setprio(0);                                                      \
    _Pragma("unroll")                                                                   \
    for (int nt=0;nt<4;nt++){                                                           \
      float p0 = fexp2(fmaf(sacc[nt][0], SCL2E, comb[nt][0]));                          \
      float p1 = fexp2(fmaf(sacc[nt][1], SCL2E, comb[nt][1]));                          \
      float p2 = fexp2(fmaf(sacc[nt][2], SCL2E, comb[nt][2]));                          \
      float p3 = fexp2(fmaf(sacc[nt][3], SCL2E, comb[nt][3]));                          \
      psum += (p0+p1)+(p2+p3);                                                          \
      uint2 pk;                                                                         \
      pk.x = cvt_pk_bf16(p0,p1);                                                        \
      pk.y = cvt_pk_bf16(p2,p3);                                                        \
      *(uint2*)&pw[lq*64 + ((nt*16 + lg*4) ^ swz)] = pk;                                \
    }                                                                                   \
    _Pragma("unroll")                                                                   \
    for (int kk=0;kk<2;kk++){                                                           \
      bf16x8 pa = *(const bf16x8*)&pw[lq*64 + ((kk*32 + lg*8) ^ swz)];                  \
      __builtin_amdgcn_s_setprio(1);                                                    \
      _Pragma("unroll")                                                                 \
      for (int nt=0;nt<4;nt++){                                                         \
        int vrow = nt*16 + lq;                                                          \
        bf16x8 vf = *(const bf16x8*)&VTs[P_][vrow*64 + (((kk*4+lg) ^ (vrow&7))*8)];     \
        oacc[nt] = __builtin_amdgcn_mfma_f32_16x16x32_bf16(pa, vf, oacc[nt], 0,0,0);    \
      }                                                                                 \
      __builtin_amdgcn_s_setprio(0);                                                    \
    }                                                                                   \
  }

// per tile: stage(kt+1) -> vmcnt(7) [waits stage(kt)+raw(kt), leaves raw(kt+1)4+stage(kt+1)3]
//           -> barrier -> combine(kt) -> raw(kt+2) -> compute(kt) -> barrier
#define TILE(kt_, cur_, RP_, DOSTAGE, DORAW, VMFULL)                                    \
  {                                                                                     \
    if (DOSTAGE) ATTN_STAGE((cur_)^1, (kt_)+1)                                          \
    if (VMFULL) { asm volatile("s_waitcnt vmcnt(7)" ::: "memory"); }                    \
    else        { asm volatile("s_waitcnt vmcnt(0)" ::: "memory"); }                    \
    __builtin_amdgcn_s_barrier();                                                       \
    ATTN_COMBINE(RP_, cur_)                                                             \
    if (DORAW) ATTN_RAW(RP_, (kt_)+2)                                                   \
    ATTN_COMPUTE(cur_)                                                                  \
    __builtin_amdgcn_s_barrier();                                                       \
  }

  // prologue: stage tile0, bias raws for tiles 0 and 1
  ATTN_STAGE(0, 0)
  ATTN_RAW(RA, 0)
  ATTN_RAW(RB, 1)

  for (int kb=0; kb<14; kb+=2){
    TILE(kb+0, 0, RA, 1, 1, 1)
    TILE(kb+1, 1, RB, 1, 1, 1)
  }
  TILE(14, 0, RA, 1, 0, 1)
  TILE(15, 1, RB, 0, 0, 0)

  // finalize: reduce denominator across lg-groups, divide, store
  float lsum = psum;
  lsum += __shfl_xor(lsum, 16);
  lsum += __shfl_xor(lsum, 32);
  #pragma unroll
  for (int r=0;r<4;r++){
    float lr = __shfl(lsum, lg*4 + r);
    float linv = 1.f/lr;
    int qrow = q0 + lg*4 + r;
    #pragma unroll
    for (int nt=0;nt<4;nt++){
      Oout[((size_t)(b*1024 + qrow))*2048 + h*64 + nt*16 + lq] = f2bf(oacc[nt][r]*linv);
    }
  }
#undef TILE
#undef ATTN_COMPUTE
#undef ATTN_COMBINE
#undef ATTN_RAW
#undef ATTN_STAGE
}

extern "C" void kernel_launch(void* const* d_in, const int* in_sizes, int n_in,
                              void* d_out, int out_size, void* d_ws, size_t ws_size,
                              hipStream_t stream){
  (void)in_sizes; (void)n_in; (void)out_size; (void)ws_size;
  const float* query = (const float*)d_in[0];
  const float* key   = (const float*)d_in[1];
  const float* value = (const float*)d_in[2];
  const float* mask  = (const float*)d_in[3];
  const float* pbias = (const float*)d_in[4];
  const float* Wq = (const float*)d_in[5];
  const float* bq = (const float*)d_in[6];
  const float* Wk = (const float*)d_in[7];
  const float* bk = (const float*)d_in[8];
  const float* Wv = (const float*)d_in[9];
  const float* bv = (const float*)d_in[10];
  const float* Wo = (const float*)d_in[11];
  const float* bo = (const float*)d_in[12];
  char* ws = (char*)d_ws;
  const size_t MB = (size_t)1<<20;
  unsigned short* qbf = (unsigned short*)(ws + 0*MB);
  unsigned short* kbf = (unsigned short*)(ws + 8*MB);
  unsigned short* vbf = (unsigned short*)(ws + 16*MB);
  unsigned short* WqT = (unsigned short*)(ws + 24*MB);
  unsigned short* WkT = (unsigned short*)(ws + 32*MB);
  unsigned short* WvT = (unsigned short*)(ws + 34*MB);
  unsigned short* WoT = (unsigned short*)(ws + 36*MB);
  unsigned short* Qp  = (unsigned short*)(ws + 44*MB);
  unsigned short* Kp  = (unsigned short*)(ws + 52*MB);
  unsigned short* VTb = (unsigned short*)(ws + 54*MB);
  unsigned short* Aout= (unsigned short*)(ws + 56*MB);

  cvt3_k<<<dim3(2048,3),256,0,stream>>>(query, key, value, qbf, kbf, vbf, 524288);
  wtrans_all<<<2560,256,0,stream>>>(Wq, Wk, Wv, Wo, WqT, WkT, WvT, WoT);
  qkv64<<<1536,256,0,stream>>>(qbf, kbf, vbf, WqT, WkT, WvT, bq, bk, bv, Qp, Kp, VTb);
  attn_k<<<512,512,0,stream>>>(Qp, Kp, VTb, pbias, mask, Aout);
  oproj64<<<dim3(32,32),256,0,stream>>>(Aout, WoT, bo, (float*)d_out);
}

// Round 11
// 152.606 us; speedup vs baseline: 1.2930x; 1.0075x over previous
//
#include <hip/hip_runtime.h>
#include <stdint.h>

// NOTE: d_ws usage is capped at 64 MB (round-9 lesson).
// Round 11: attn_k is a byte-exact revert to round 8 (74.4 µs, passing).
// Rounds 9/10's batch-sharing restructure fails correctness for reasons two
// audits couldn't locate — abandoned pending a debug-friendly retry.

#define DEVI __device__ __forceinline__

typedef __attribute__((ext_vector_type(8))) short bf16x8;
typedef __attribute__((ext_vector_type(4))) float f32x4;
typedef __attribute__((ext_vector_type(4))) float flt4;
typedef __attribute__((ext_vector_type(8))) unsigned short u16x8;
typedef __attribute__((ext_vector_type(4))) unsigned short u16x4;

DEVI unsigned short f2bf(float f){
  union{float f;uint32_t u;}v; v.f=f;
  uint32_t u=v.u;
  u += 0x7FFFu + ((u>>16)&1u);
  return (unsigned short)(u>>16);
}

DEVI uint32_t cvt_pk_bf16(float lo, float hi){
  uint32_t r;
  asm("v_cvt_pk_bf16_f32 %0, %1, %2" : "=v"(r) : "v"(lo), "v"(hi));
  return r;
}

DEVI float fexp2(float x){
#if __has_builtin(__builtin_amdgcn_exp2f)
  return __builtin_amdgcn_exp2f(x);
#else
  return exp2f(x);
#endif
}

DEVI void gload16(const void* g, void* l){
  __builtin_amdgcn_global_load_lds((const __attribute__((address_space(1))) void*)g,
                                   (__attribute__((address_space(3))) void*)l, 16, 0, 0);
}

// ---------------- merged preprocessing: activations fp32->bf16 + weight transposes ----------------
// blocks 0..6143: cvt (z = id>>11 selects q/k/v, 2048 blocks each, 8 elems/thread)
// blocks 6144..8703: wtrans (2560 blocks as in round 8's wtrans_all)
__global__ void prep_k(const float* __restrict__ q, const float* __restrict__ k,
                       const float* __restrict__ v,
                       unsigned short* __restrict__ qb, unsigned short* __restrict__ kb,
                       unsigned short* __restrict__ vb,
                       const float* __restrict__ Wq, const float* __restrict__ Wk,
                       const float* __restrict__ Wv, const float* __restrict__ Wo,
                       unsigned short* __restrict__ WqT, unsigned short* __restrict__ WkT,
                       unsigned short* __restrict__ WvT, unsigned short* __restrict__ WoT){
  __shared__ float tile[64][65];
  int bid = blockIdx.x;
  if (bid < 6144){
    int z = bid>>11;
    int i = (bid&2047)*256 + threadIdx.x;   // < 524288 exactly
    const float* src = z==0 ? q : (z==1 ? k : v);
    unsigned short* dst = z==0 ? qb : (z==1 ? kb : vb);
    const flt4* s = (const flt4*)src;
    flt4 a = s[2*i], b = s[2*i+1];
    u16x8 o;
    o[0]=f2bf(a.x); o[1]=f2bf(a.y); o[2]=f2bf(a.z); o[3]=f2bf(a.w);
    o[4]=f2bf(b.x); o[5]=f2bf(b.y); o[6]=f2bf(b.z); o[7]=f2bf(b.w);
    ((u16x8*)dst)[i] = o;
    return;
  }
  int id = bid - 6144;
  const int K = 2048;
  const float* W; unsigned short* WT; int N, tt;
  if (id < 1024)      { W=Wq; WT=WqT; N=2048; tt=id; }
  else if (id < 1280) { W=Wk; WT=WkT; N=512;  tt=id-1024; }
  else if (id < 1536) { W=Wv; WT=WvT; N=512;  tt=id-1280; }
  else                { W=Wo; WT=WoT; N=2048; tt=id-1536; }
  int sh = (N==2048) ? 5 : 3;
  int n0 = (tt & ((1<<sh)-1))*64, k0 = (tt >> sh)*64;
  int t = threadIdx.x;
  int r = t>>4, c4 = (t&15)*4;
  #pragma unroll
  for (int i=0;i<4;i++){
    flt4 vv = *(const flt4*)&W[(size_t)(k0 + r + i*16)*N + n0 + c4];
    tile[r+i*16][c4+0]=vv.x; tile[r+i*16][c4+1]=vv.y; tile[r+i*16][c4+2]=vv.z; tile[r+i*16][c4+3]=vv.w;
  }
  __syncthreads();
  #pragma unroll
  for (int i=0;i<4;i++){
    int rn = r + i*16;
    u16x4 o;
    o[0]=f2bf(tile[c4+0][rn]); o[1]=f2bf(tile[c4+1][rn]);
    o[2]=f2bf(tile[c4+2][rn]); o[3]=f2bf(tile[c4+3][rn]);
    *(u16x4*)&WT[(size_t)(n0+rn)*K + k0 + c4] = o;
  }
}

// ================= shared 64x64 GEMM K-step (XOR-swizzled LDS, 2-way banks) =================
#define GEMM64_KSTEP(A_, BT_, K_)                                              \
    __syncthreads();                                                           \
    _Pragma("unroll")                                                          \
    for (int j=0;j<2;j++){                                                     \
      int cid = (j*4+w)*64 + l;                                                \
      int row = cid>>3, sl = cid&7;                                            \
      int gsl = sl ^ (row&7);                                                  \
      gload16(&A_ [(size_t)(m0+row)*K_ + k0 + gsl*8], &As[(j*4+w)*512]);       \
      gload16(&BT_[(size_t)(n0+row)*K_ + k0 + gsl*8], &Bs[(j*4+w)*512]);       \
    }                                                                          \
    __syncthreads();                                                           \
    _Pragma("unroll")                                                          \
    for (int kk=0;kk<2;kk++){                                                  \
      bf16x8 af[2], bfv[2];                                                    \
      _Pragma("unroll")                                                        \
      for (int mt=0;mt<2;mt++){                                                \
        int row = wr+mt*16+lq;                                                 \
        af[mt] = *(const bf16x8*)&As[row*64 + (((kk*4+lg)^(lq&7))*8)];         \
      }                                                                        \
      _Pragma("unroll")                                                        \
      for (int nt=0;nt<2;nt++){                                                \
        int row = wc+nt*16+lq;                                                 \
        bfv[nt] = *(const bf16x8*)&Bs[row*64 + (((kk*4+lg)^(lq&7))*8)];        \
      }                                                                        \
      _Pragma("unroll")                                                        \
      for (int mt=0;mt<2;mt++)                                                 \
        _Pragma("unroll")                                                      \
        for (int nt=0;nt<2;nt++)                                               \
          acc[mt][nt] = __builtin_amdgcn_mfma_f32_16x16x32_bf16(af[mt], bfv[nt], acc[mt][nt], 0,0,0); \
    }

// ---------------- fused Q,K,V projections: 1536 WGs, 64x64 tiles ----------------
__global__ __launch_bounds__(256) void qkv64(const unsigned short* __restrict__ qbf,
    const unsigned short* __restrict__ kbf, const unsigned short* __restrict__ vbf,
    const unsigned short* __restrict__ WqT, const unsigned short* __restrict__ WkT,
    const unsigned short* __restrict__ WvT,
    const float* __restrict__ bq, const float* __restrict__ bk, const float* __restrict__ bv,
    unsigned short* __restrict__ Qp, unsigned short* __restrict__ Kp, unsigned short* __restrict__ VTb){
  __shared__ unsigned short As[64*64];
  __shared__ unsigned short Bs[64*64];
  const int K = 2048;
  int id = blockIdx.x;
  const unsigned short *A, *BT; const float* bias; int N, op, tt;
  if (id < 1024)      { op=0; A=qbf; BT=WqT; bias=bq; N=2048; tt=id; }
  else if (id < 1280) { op=1; A=kbf; BT=WkT; bias=bk; N=512;  tt=id-1024; }
  else                { op=2; A=vbf; BT=WvT; bias=bv; N=512;  tt=id-1280; }
  int sh = (N==2048) ? 5 : 3;
  int n0 = (tt & ((1<<sh)-1))*64, m0 = (tt >> sh)*64;
  int t = threadIdx.x, w = t>>6, l = t&63;
  int lq = l&15, lg = l>>4;
  int wr = (w>>1)*32, wc = (w&1)*32;
  f32x4 acc[2][2] = {};
  for (int k0=0;k0<K;k0+=64){
    GEMM64_KSTEP(A, BT, K)
  }
  #pragma unroll
  for (int nt=0;nt<2;nt++){
    int col = n0 + wc + nt*16 + lq;
    float bvl = bias[col];
    #pragma unroll
    for (int mt=0;mt<2;mt++){
      #pragma unroll
      for (int r=0;r<4;r++){
        int row = m0 + wr + mt*16 + lg*4 + r;
        float v = acc[mt][nt][r] + bvl;
        if (op==0)      Qp[(size_t)row*2048 + col] = f2bf(v);
        else if (op==1) Kp[(size_t)row*512 + col] = f2bf(v);
        else {
          int b = row>>10, s = row&1023;
          VTb[((size_t)(b*512 + col)<<10) + s] = f2bf(v);
        }
      }
    }
  }
}

// ---------------- O projection: 1024 WGs, 64x64 tiles, fp32 out ----------------
__global__ __launch_bounds__(256) void oproj64(const unsigned short* __restrict__ A,
    const unsigned short* __restrict__ BT, const float* __restrict__ bias,
    float* __restrict__ Cout){
  __shared__ unsigned short As[64*64];
  __shared__ unsigned short Bs[64*64];
  const int K = 2048, N = 2048;
  int n0 = blockIdx.x*64, m0 = blockIdx.y*64;
  int t = threadIdx.x, w = t>>6, l = t&63;
  int lq = l&15, lg = l>>4;
  int wr = (w>>1)*32, wc = (w&1)*32;
  f32x4 acc[2][2] = {};
  for (int k0=0;k0<K;k0+=64){
    GEMM64_KSTEP(A, BT, K)
  }
  #pragma unroll
  for (int nt=0;nt<2;nt++){
    int col = n0 + wc + nt*16 + lq;
    float bvl = bias[col];
    #pragma unroll
    for (int mt=0;mt<2;mt++){
      #pragma unroll
      for (int r=0;r<4;r++){
        int row = m0 + wr + mt*16 + lg*4 + r;
        Cout[(size_t)row*N + col] = acc[mt][nt][r] + bvl;
      }
    }
  }
}

// ---------------- fused flash attention: round-8 exact (proven 74.4 us) ----------------
__global__ __launch_bounds__(512,4) void attn_k(const unsigned short* __restrict__ Q,
    const unsigned short* __restrict__ Kp, const unsigned short* __restrict__ VT,
    const float* __restrict__ pbias, const float* __restrict__ mask,
    unsigned short* __restrict__ Oout){
  __shared__ unsigned short Ks[2][4096];   // [key 64][d 64] bf16, row-XOR swizzled
  __shared__ unsigned short VTs[2][4096];  // [d 64][key 64] bf16, row-XOR swizzled
  __shared__ float Ms[2][2048];            // [qrow 32][key 64] fp32, chunk-XOR swizzled
  __shared__ unsigned short Pb[8][1024];   // wave-private P, XOR-swizzled
  int t=threadIdx.x, w=t>>6, l=t&63;
  // chunked XCD remap: logical-consecutive WGs (b pairs sharing pbias) land on one XCD
  int phys = blockIdx.x;
  int lin = (phys&7)*64 + (phys>>3);       // 512 = 8 x 64, bijective
  int qb = lin>>4, kv = (lin>>1)&7, b = lin&1;
  int h = kv*4 + (w&3);
  int qhalf = w>>2;
  int lq = l&15, lg = l>>4;
  int q0 = qb*32 + qhalf*16;
  int mr = qhalf*16 + lq;                  // this lane's row in the WG mask tile
  bf16x8 qf0, qf1;
  {
    const unsigned short* qp = &Q[((size_t)(b*1024 + q0 + lq))*2048 + h*64 + lg*8];
    qf0 = *(const bf16x8*)qp;
    qf1 = *(const bf16x8*)(qp + 32);
  }
  const float* pbase  = &pbias[((size_t)h*1024 + (q0+lq))*1024];
  const float* maskWG = &mask [((size_t)(b*1024 + qb*32))*1024];
  f32x4 oacc[4] = {};
  float psum = 0.f;
  const float L2E   = 1.4426950408889634f;
  const float SCL2E = 0.125f*1.4426950408889634f;
  const float NFM   = -16.0f*1.4426950408889634f;  // fixed softmax max = 16
  unsigned short* pw = &Pb[w][0];
  int swz = (lq&7)<<3;

  flt4 RA[4], RB[4], comb[4];

// stage K(8KB)+V(8KB)+mask(8KB): 1 gload_lds each per wave (8 waves cover the tiles)
#define ATTN_STAGE(buf_, kt_)                                                           \
  {                                                                                     \
    int c = w*64 + l;                                                                   \
    int krow = c>>3, ksl = (c&7)^(krow&7);                                              \
    gload16(&Kp[((size_t)(b*1024 + (kt_)*64 + krow))*512 + kv*64 + ksl*8], &Ks[buf_][w*512]);          \
    gload16(&VT[((size_t)(b*512 + kv*64 + krow))*1024 + (size_t)((kt_)*64 + ksl*8)], &VTs[buf_][w*512]);\
    int mrow = c>>4, msl = (c&15)^(mrow&7);                                             \
    gload16(&maskWG[(size_t)mrow*1024 + (kt_)*64 + msl*4], &Ms[buf_][w*256]);           \
  }

#define ATTN_RAW(RP_, kt_)                                                              \
  _Pragma("unroll")                                                                     \
  for (int nt=0;nt<4;nt++)                                                              \
    RP_[nt] = *(const flt4*)&pbase[(kt_)*64 + nt*16 + lg*4];

#define ATTN_COMBINE(RP_, cur_)                                                         \
  _Pragma("unroll")                                                                     \
  for (int nt=0;nt<4;nt++){                                                             \
    flt4 m4 = *(const flt4*)&Ms[cur_][mr*64 + (((nt*4+lg)^(mr&7))<<2)];                 \
    _Pragma("unroll")                                                                   \
    for (int r=0;r<4;r++)                                                               \
      comb[nt][r] = fmaf(RP_[nt][r], SCL2E, fmaf(m4[r], L2E, NFM));                     \
  }

#define ATTN_COMPUTE(P_)                                                                \
  {                                                                                     \
    f32x4 sacc[4] = {};                                                                 \
    __builtin_amdgcn_s_setprio(1);                                                      \
    _Pragma("unroll")                                                                   \
    for (int nt=0;nt<4;nt++){                                                           \
      int row = nt*16 + lq;                                                             \
      bf16x8 kf0 = *(const bf16x8*)&Ks[P_][row*64 + (( lg    ^ (row&7))*8)];            \
      bf16x8 kf1 = *(const bf16x8*)&Ks[P_][row*64 + (((4+lg) ^ (row&7))*8)];            \
      sacc[nt] = __builtin_amdgcn_mfma_f32_16x16x32_bf16(kf0, qf0, sacc[nt], 0,0,0);    \
      sacc[nt] = __builtin_amdgcn_mfma_f32_16x16x32_bf16(kf1, qf1, sacc[nt], 0,0,0);    \
    }                                                                                   \
    __builtin_amdgcn_s_setprio(0);                                                      \
    _Pragma("unroll")                                                                   \
    for (int nt=0;nt<4;nt++){                                                           \
      float p0 = fexp2(fmaf(sacc[nt][0], SCL2E, comb[nt][0]));                          \
      float p1 = fexp2(fmaf(sacc[nt][1], SCL2E, comb[nt][1]));                          \
      float p2 = fexp2(fmaf(sacc[nt][2], SCL2E, comb[nt][2]));                          \
      float p3 = fexp2(fmaf(sacc[nt][3], SCL2E, comb[nt][3]));                          \
      psum += (p0+p1)+(p2+p3);                                                          \
      uint2 pk;                                                                         \
      pk.x = cvt_pk_bf16(p0,p1);                                                        \
      pk.y = cvt_pk_bf16(p2,p3);                                                        \
      *(uint2*)&pw[lq*64 + ((nt*16 + lg*4) ^ swz)] = pk;                                \
    }                                                                                   \
    _Pragma("unroll")                                                                   \
    for (int kk=0;kk<2;kk++){                                                           \
      bf16x8 pa = *(const bf16x8*)&pw[lq*64 + ((kk*32 + lg*8) ^ swz)];                  \
      __builtin_amdgcn_s_setprio(1);                                                    \
      _Pragma("unroll")                                                                 \
      for (int nt=0;nt<4;nt++){                                                         \
        int vrow = nt*16 + lq;                                                          \
        bf16x8 vf = *(const bf16x8*)&VTs[P_][vrow*64 + (((kk*4+lg) ^ (vrow&7))*8)];     \
        oacc[nt] = __builtin_amdgcn_mfma_f32_16x16x32_bf16(pa, vf, oacc[nt], 0,0,0);    \
      }                                                                                 \
      __builtin_amdgcn_s_setprio(0);                                                    \
    }                                                                                   \
  }

// per tile: stage(kt+1) -> vmcnt(7) [waits stage(kt)+raw(kt), leaves raw(kt+1)4+stage(kt+1)3]
//           -> barrier -> combine(kt) -> raw(kt+2) -> compute(kt) -> barrier
#define TILE(kt_, cur_, RP_, DOSTAGE, DORAW, VMFULL)                                    \
  {                                                                                     \
    if (DOSTAGE) ATTN_STAGE((cur_)^1, (kt_)+1)                                          \
    if (VMFULL) { asm volatile("s_waitcnt vmcnt(7)" ::: "memory"); }                    \
    else        { asm volatile("s_waitcnt vmcnt(0)" ::: "memory"); }                    \
    __builtin_amdgcn_s_barrier();                                                       \
    ATTN_COMBINE(RP_, cur_)                                                             \
    if (DORAW) ATTN_RAW(RP_, (kt_)+2)                                                   \
    ATTN_COMPUTE(cur_)                                                                  \
    __builtin_amdgcn_s_barrier();                                                       \
  }

  // prologue: stage tile0, bias raws for tiles 0 and 1
  ATTN_STAGE(0, 0)
  ATTN_RAW(RA, 0)
  ATTN_RAW(RB, 1)

  for (int kb=0; kb<14; kb+=2){
    TILE(kb+0, 0, RA, 1, 1, 1)
    TILE(kb+1, 1, RB, 1, 1, 1)
  }
  TILE(14, 0, RA, 1, 0, 1)
  TILE(15, 1, RB, 0, 0, 0)

  // finalize: reduce denominator across lg-groups, divide, store
  float lsum = psum;
  lsum += __shfl_xor(lsum, 16);
  lsum += __shfl_xor(lsum, 32);
  #pragma unroll
  for (int r=0;r<4;r++){
    float lr = __shfl(lsum, lg*4 + r);
    float linv = 1.f/lr;
    int qrow = q0 + lg*4 + r;
    #pragma unroll
    for (int nt=0;nt<4;nt++){
      Oout[((size_t)(b*1024 + qrow))*2048 + h*64 + nt*16 + lq] = f2bf(oacc[nt][r]*linv);
    }
  }
#undef TILE
#undef ATTN_COMPUTE
#undef ATTN_COMBINE
#undef ATTN_RAW
#undef ATTN_STAGE
}

extern "C" void kernel_launch(void* const* d_in, const int* in_sizes, int n_in,
                              void* d_out, int out_size, void* d_ws, size_t ws_size,
                              hipStream_t stream){
  (void)in_sizes; (void)n_in; (void)out_size; (void)ws_size;
  const float* query = (const float*)d_in[0];
  const float* key   = (const float*)d_in[1];
  const float* value = (const float*)d_in[2];
  const float* mask  = (const float*)d_in[3];
  const float* pbias = (const float*)d_in[4];
  const float* Wq = (const float*)d_in[5];
  const float* bq = (const float*)d_in[6];
  const float* Wk = (const float*)d_in[7];
  const float* bk = (const float*)d_in[8];
  const float* Wv = (const float*)d_in[9];
  const float* bv = (const float*)d_in[10];
  const float* Wo = (const float*)d_in[11];
  const float* bo = (const float*)d_in[12];
  char* ws = (char*)d_ws;
  const size_t MB = (size_t)1<<20;
  unsigned short* qbf = (unsigned short*)(ws + 0*MB);
  unsigned short* kbf = (unsigned short*)(ws + 8*MB);
  unsigned short* vbf = (unsigned short*)(ws + 16*MB);
  unsigned short* WqT = (unsigned short*)(ws + 24*MB);
  unsigned short* WkT = (unsigned short*)(ws + 32*MB);
  unsigned short* WvT = (unsigned short*)(ws + 34*MB);
  unsigned short* WoT = (unsigned short*)(ws + 36*MB);
  unsigned short* Qp  = (unsigned short*)(ws + 44*MB);
  unsigned short* Kp  = (unsigned short*)(ws + 52*MB);
  unsigned short* VTb = (unsigned short*)(ws + 54*MB);
  unsigned short* Aout= (unsigned short*)(ws + 56*MB);

  prep_k<<<8704,256,0,stream>>>(query, key, value, qbf, kbf, vbf,
                                Wq, Wk, Wv, Wo, WqT, WkT, WvT, WoT);
  qkv64<<<1536,256,0,stream>>>(qbf, kbf, vbf, WqT, WkT, WvT, bq, bk, bv, Qp, Kp, VTb);
  attn_k<<<512,512,0,stream>>>(Qp, Kp, VTb, pbias, mask, Aout);
  oproj64<<<dim3(32,32),256,0,stream>>>(Aout, WoT, bo, (float*)d_out);
}

// Round 12
// 151.001 us; speedup vs baseline: 1.3067x; 1.0106x over previous
//
#include <hip/hip_runtime.h>
#include <stdint.h>

// NOTES: (1) d_ws capped at 64 MB (round-9 lesson). (2) Working theory from
// rounds 9/10: static __shared__ > 64 KB correlates perfectly with the two
// corruption failures (9/9 passing kernels <= 64 KB). This round's attn_k
// retests batch-sharing at LDS = 56 KB (KVBLK=32).

#define DEVI __device__ __forceinline__

typedef __attribute__((ext_vector_type(8))) short bf16x8;
typedef __attribute__((ext_vector_type(4))) float f32x4;
typedef __attribute__((ext_vector_type(4))) float flt4;
typedef __attribute__((ext_vector_type(8))) unsigned short u16x8;
typedef __attribute__((ext_vector_type(4))) unsigned short u16x4;

DEVI unsigned short f2bf(float f){
  union{float f;uint32_t u;}v; v.f=f;
  uint32_t u=v.u;
  u += 0x7FFFu + ((u>>16)&1u);
  return (unsigned short)(u>>16);
}

DEVI uint32_t cvt_pk_bf16(float lo, float hi){
  uint32_t r;
  asm("v_cvt_pk_bf16_f32 %0, %1, %2" : "=v"(r) : "v"(lo), "v"(hi));
  return r;
}

DEVI float fexp2(float x){
#if __has_builtin(__builtin_amdgcn_exp2f)
  return __builtin_amdgcn_exp2f(x);
#else
  return exp2f(x);
#endif
}

DEVI void gload16(const void* g, void* l){
  __builtin_amdgcn_global_load_lds((const __attribute__((address_space(1))) void*)g,
                                   (__attribute__((address_space(3))) void*)l, 16, 0, 0);
}

// ---------------- merged preprocessing: activations fp32->bf16 + weight transposes ----------------
__global__ void prep_k(const float* __restrict__ q, const float* __restrict__ k,
                       const float* __restrict__ v,
                       unsigned short* __restrict__ qb, unsigned short* __restrict__ kb,
                       unsigned short* __restrict__ vb,
                       const float* __restrict__ Wq, const float* __restrict__ Wk,
                       const float* __restrict__ Wv, const float* __restrict__ Wo,
                       unsigned short* __restrict__ WqT, unsigned short* __restrict__ WkT,
                       unsigned short* __restrict__ WvT, unsigned short* __restrict__ WoT){
  __shared__ float tile[64][65];
  int bid = blockIdx.x;
  if (bid < 6144){
    int z = bid>>11;
    int i = (bid&2047)*256 + threadIdx.x;
    const float* src = z==0 ? q : (z==1 ? k : v);
    unsigned short* dst = z==0 ? qb : (z==1 ? kb : vb);
    const flt4* s = (const flt4*)src;
    flt4 a = s[2*i], b = s[2*i+1];
    u16x8 o;
    o[0]=f2bf(a.x); o[1]=f2bf(a.y); o[2]=f2bf(a.z); o[3]=f2bf(a.w);
    o[4]=f2bf(b.x); o[5]=f2bf(b.y); o[6]=f2bf(b.z); o[7]=f2bf(b.w);
    ((u16x8*)dst)[i] = o;
    return;
  }
  int id = bid - 6144;
  const int K = 2048;
  const float* W; unsigned short* WT; int N, tt;
  if (id < 1024)      { W=Wq; WT=WqT; N=2048; tt=id; }
  else if (id < 1280) { W=Wk; WT=WkT; N=512;  tt=id-1024; }
  else if (id < 1536) { W=Wv; WT=WvT; N=512;  tt=id-1280; }
  else                { W=Wo; WT=WoT; N=2048; tt=id-1536; }
  int sh = (N==2048) ? 5 : 3;
  int n0 = (tt & ((1<<sh)-1))*64, k0 = (tt >> sh)*64;
  int t = threadIdx.x;
  int r = t>>4, c4 = (t&15)*4;
  #pragma unroll
  for (int i=0;i<4;i++){
    flt4 vv = *(const flt4*)&W[(size_t)(k0 + r + i*16)*N + n0 + c4];
    tile[r+i*16][c4+0]=vv.x; tile[r+i*16][c4+1]=vv.y; tile[r+i*16][c4+2]=vv.z; tile[r+i*16][c4+3]=vv.w;
  }
  __syncthreads();
  #pragma unroll
  for (int i=0;i<4;i++){
    int rn = r + i*16;
    u16x4 o;
    o[0]=f2bf(tile[c4+0][rn]); o[1]=f2bf(tile[c4+1][rn]);
    o[2]=f2bf(tile[c4+2][rn]); o[3]=f2bf(tile[c4+3][rn]);
    *(u16x4*)&WT[(size_t)(n0+rn)*K + k0 + c4] = o;
  }
}

// ================= shared 64x64 GEMM K-step (XOR-swizzled LDS, 2-way banks) =================
#define GEMM64_KSTEP(A_, BT_, K_)                                              \
    __syncthreads();                                                           \
    _Pragma("unroll")                                                          \
    for (int j=0;j<2;j++){                                                     \
      int cid = (j*4+w)*64 + l;                                                \
      int row = cid>>3, sl = cid&7;                                            \
      int gsl = sl ^ (row&7);                                                  \
      gload16(&A_ [(size_t)(m0+row)*K_ + k0 + gsl*8], &As[(j*4+w)*512]);       \
      gload16(&BT_[(size_t)(n0+row)*K_ + k0 + gsl*8], &Bs[(j*4+w)*512]);       \
    }                                                                          \
    __syncthreads();                                                           \
    _Pragma("unroll")                                                          \
    for (int kk=0;kk<2;kk++){                                                  \
      bf16x8 af[2], bfv[2];                                                    \
      _Pragma("unroll")                                                        \
      for (int mt=0;mt<2;mt++){                                                \
        int row = wr+mt*16+lq;                                                 \
        af[mt] = *(const bf16x8*)&As[row*64 + (((kk*4+lg)^(lq&7))*8)];         \
      }                                                                        \
      _Pragma("unroll")                                                        \
      for (int nt=0;nt<2;nt++){                                                \
        int row = wc+nt*16+lq;                                                 \
        bfv[nt] = *(const bf16x8*)&Bs[row*64 + (((kk*4+lg)^(lq&7))*8)];        \
      }                                                                        \
      _Pragma("unroll")                                                        \
      for (int mt=0;mt<2;mt++)                                                 \
        _Pragma("unroll")                                                      \
        for (int nt=0;nt<2;nt++)                                               \
          acc[mt][nt] = __builtin_amdgcn_mfma_f32_16x16x32_bf16(af[mt], bfv[nt], acc[mt][nt], 0,0,0); \
    }

// ---------------- fused Q,K,V projections: 1536 WGs, 64x64 tiles ----------------
__global__ __launch_bounds__(256) void qkv64(const unsigned short* __restrict__ qbf,
    const unsigned short* __restrict__ kbf, const unsigned short* __restrict__ vbf,
    const unsigned short* __restrict__ WqT, const unsigned short* __restrict__ WkT,
    const unsigned short* __restrict__ WvT,
    const float* __restrict__ bq, const float* __restrict__ bk, const float* __restrict__ bv,
    unsigned short* __restrict__ Qp, unsigned short* __restrict__ Kp, unsigned short* __restrict__ VTb){
  __shared__ unsigned short As[64*64];
  __shared__ unsigned short Bs[64*64];
  const int K = 2048;
  int id = blockIdx.x;
  const unsigned short *A, *BT; const float* bias; int N, op, tt;
  if (id < 1024)      { op=0; A=qbf; BT=WqT; bias=bq; N=2048; tt=id; }
  else if (id < 1280) { op=1; A=kbf; BT=WkT; bias=bk; N=512;  tt=id-1024; }
  else                { op=2; A=vbf; BT=WvT; bias=bv; N=512;  tt=id-1280; }
  int sh = (N==2048) ? 5 : 3;
  int n0 = (tt & ((1<<sh)-1))*64, m0 = (tt >> sh)*64;
  int t = threadIdx.x, w = t>>6, l = t&63;
  int lq = l&15, lg = l>>4;
  int wr = (w>>1)*32, wc = (w&1)*32;
  f32x4 acc[2][2] = {};
  for (int k0=0;k0<K;k0+=64){
    GEMM64_KSTEP(A, BT, K)
  }
  #pragma unroll
  for (int nt=0;nt<2;nt++){
    int col = n0 + wc + nt*16 + lq;
    float bvl = bias[col];
    #pragma unroll
    for (int mt=0;mt<2;mt++){
      #pragma unroll
      for (int r=0;r<4;r++){
        int row = m0 + wr + mt*16 + lg*4 + r;
        float v = acc[mt][nt][r] + bvl;
        if (op==0)      Qp[(size_t)row*2048 + col] = f2bf(v);
        else if (op==1) Kp[(size_t)row*512 + col] = f2bf(v);
        else {
          int b = row>>10, s = row&1023;
          VTb[((size_t)(b*512 + col)<<10) + s] = f2bf(v);
        }
      }
    }
  }
}

// ---------------- O projection: 1024 WGs, 64x64 tiles, fp32 out ----------------
__global__ __launch_bounds__(256) void oproj64(const unsigned short* __restrict__ A,
    const unsigned short* __restrict__ BT, const float* __restrict__ bias,
    float* __restrict__ Cout){
  __shared__ unsigned short As[64*64];
  __shared__ unsigned short Bs[64*64];
  const int K = 2048, N = 2048;
  int n0 = blockIdx.x*64, m0 = blockIdx.y*64;
  int t = threadIdx.x, w = t>>6, l = t&63;
  int lq = l&15, lg = l>>4;
  int wr = (w>>1)*32, wc = (w&1)*32;
  f32x4 acc[2][2] = {};
  for (int k0=0;k0<K;k0+=64){
    GEMM64_KSTEP(A, BT, K)
  }
  #pragma unroll
  for (int nt=0;nt<2;nt++){
    int col = n0 + wc + nt*16 + lq;
    float bvl = bias[col];
    #pragma unroll
    for (int mt=0;mt<2;mt++){
      #pragma unroll
      for (int r=0;r<4;r++){
        int row = m0 + wr + mt*16 + lg*4 + r;
        Cout[(size_t)row*N + col] = acc[mt][nt][r] + bvl;
      }
    }
  }
}

// ---------------- fused flash attention: batch-sharing, KVBLK=32, LDS 56KB ----------------
// WG = (qb: 32 q-rows, kv-group), BOTH batches; 8 waves = 4 heads x 2 q-halves.
// Bias registers shared across batches: each (h,q,k) pbias element read once chip-wide.
// 32 k-tiles of 32 keys; per-tile order mirrors the proven round-8 TILE.
__global__ __launch_bounds__(512,2) void attn_k(const unsigned short* __restrict__ Q,
    const unsigned short* __restrict__ Kp, const unsigned short* __restrict__ VT,
    const float* __restrict__ pbias, const float* __restrict__ mask,
    unsigned short* __restrict__ Oout){
  __shared__ unsigned short Ks[2][2][2048];  // 16KB [buf][batch][key 32][d 64], chunk-XOR swz
  __shared__ unsigned short VTs[2][4096];    // 16KB [buf][d 64][bc 8: batch*4+kchunk][8 key]
  __shared__ float Ms[2][2][1024];           // 16KB [buf][batch][qrow 32][key 32], chunk-XOR swz
  __shared__ unsigned short Pb[8][512];      //  8KB [wave][16 q][32 key], XOR swz
  int t=threadIdx.x, w=t>>6, l=t&63;
  int kv = blockIdx.x & 7;                   // XCD x owns kv-group x
  int qb = blockIdx.x >> 3;
  int h = kv*4 + (w&3);
  int qhalf = w>>2;
  int lq = l&15, lg = l>>4;
  int q0 = qb*32 + qhalf*16;
  int mr = qhalf*16 + lq;
  bf16x8 qfA0, qfA1, qfB0, qfB1;
  {
    const unsigned short* qp = &Q[((size_t)(q0 + lq))*2048 + h*64 + lg*8];
    qfA0 = *(const bf16x8*)qp;  qfA1 = *(const bf16x8*)(qp + 32);
    qp += (size_t)1024*2048;
    qfB0 = *(const bf16x8*)qp;  qfB1 = *(const bf16x8*)(qp + 32);
  }
  const float* pbase = &pbias[((size_t)h*1024 + (q0+lq))*1024];
  f32x4 oaccA[4] = {}, oaccB[4] = {};
  float psumA = 0.f, psumB = 0.f;
  const float L2E   = 1.4426950408889634f;
  const float SCL2E = 0.125f*1.4426950408889634f;
  const float NFM   = -16.0f*1.4426950408889634f;  // fixed softmax max = 16
  unsigned short* pw = &Pb[w][0];
  int swz = (lq&3)<<3;                       // P swizzle (shorts)

  flt4 RA[2], RB[2], comb[2][2];

// 3 gload16/wave: K (1KB), V (1KB), mask (1KB); dest = flat base + w*1KB (lane id x16B)
#define ATTN_STAGE(buf_, kt_)                                                            \
  {                                                                                      \
    { int bb = w>>2; int row = (w&3)*8 + (l>>3); int ch = (l&7)^(row&7);                 \
      gload16(&Kp[((size_t)(bb*1024 + (kt_)*32 + row))*512 + kv*64 + ch*8],              \
              &Ks[buf_][0][0] + w*512); }                                                \
    { int row = w*8 + (l>>3); int g = (l&7)^(row&7);                                     \
      gload16(&VT[((size_t)((g>>2)*512 + kv*64 + row))*1024 + (kt_)*32 + (g&3)*8],       \
              &VTs[buf_][0] + w*512); }                                                  \
    { int bb = w>>2; int row = (w&3)*8 + (l>>3); int ch = (l&7)^(row&7);                 \
      gload16(&mask[((size_t)(bb*1024 + qb*32 + row))*1024 + (kt_)*32 + ch*4],           \
              &Ms[buf_][0][0] + w*256); }                                                \
  }

#define ATTN_RAW(RP_, kt_)                                                               \
  _Pragma("unroll")                                                                      \
  for (int nt=0;nt<2;nt++)                                                               \
    RP_[nt] = *(const flt4*)&pbase[(kt_)*32 + nt*16 + lg*4];

// comb for BOTH batches up front (bias regs then free for RAW(t+2))
#define ATTN_COMBINE(RP_, cur_)                                                          \
  _Pragma("unroll")                                                                      \
  for (int bb=0;bb<2;bb++)                                                               \
    _Pragma("unroll")                                                                    \
    for (int nt=0;nt<2;nt++){                                                            \
      flt4 m4 = *(const flt4*)&Ms[cur_][bb][mr*32 + (((nt*4+lg)^(mr&7))<<2)];            \
      _Pragma("unroll")                                                                  \
      for (int r=0;r<4;r++)                                                              \
        comb[bb][nt][r] = fmaf(RP_[nt][r], SCL2E, fmaf(m4[r], L2E, NFM));                \
    }

#define COMPUTE_BATCH(P_, bb_, QF0_, QF1_, OACC_, PS_)                                   \
  {                                                                                      \
    f32x4 sacc[2] = {};                                                                  \
    __builtin_amdgcn_s_setprio(1);                                                       \
    _Pragma("unroll")                                                                    \
    for (int nt=0;nt<2;nt++){                                                            \
      int row = nt*16 + lq;                                                              \
      bf16x8 kf0 = *(const bf16x8*)&Ks[P_][bb_][row*64 + (( lg    ^ (row&7))*8)];        \
      bf16x8 kf1 = *(const bf16x8*)&Ks[P_][bb_][row*64 + (((4+lg) ^ (row&7))*8)];        \
      sacc[nt] = __builtin_amdgcn_mfma_f32_16x16x32_bf16(kf0, QF0_, sacc[nt], 0,0,0);    \
      sacc[nt] = __builtin_amdgcn_mfma_f32_16x16x32_bf16(kf1, QF1_, sacc[nt], 0,0,0);    \
    }                                                                                    \
    __builtin_amdgcn_s_setprio(0);                                                       \
    _Pragma("unroll")                                                                    \
    for (int nt=0;nt<2;nt++){                                                            \
      float p0 = fexp2(fmaf(sacc[nt][0], SCL2E, comb[bb_][nt][0]));                      \
      float p1 = fexp2(fmaf(sacc[nt][1], SCL2E, comb[bb_][nt][1]));                      \
      float p2 = fexp2(fmaf(sacc[nt][2], SCL2E, comb[bb_][nt][2]));                      \
      float p3 = fexp2(fmaf(sacc[nt][3], SCL2E, comb[bb_][nt][3]));                      \
      PS_ += (p0+p1)+(p2+p3);                                                            \
      uint2 pk;                                                                          \
      pk.x = cvt_pk_bf16(p0,p1);                                                         \
      pk.y = cvt_pk_bf16(p2,p3);                                                         \
      *(uint2*)&pw[lq*32 + ((nt*16 + lg*4) ^ swz)] = pk;                                 \
    }                                                                                    \
    {                                                                                    \
      bf16x8 pa = *(const bf16x8*)&pw[lq*32 + ((lg*8) ^ swz)];                           \
      __builtin_amdgcn_s_setprio(1);                                                     \
      _Pragma("unroll")                                                                  \
      for (int nt=0;nt<4;nt++){                                                          \
        int vrow = nt*16 + lq;                                                           \
        bf16x8 vf = *(const bf16x8*)&VTs[P_][vrow*64 + ((((bb_)*4+lg) ^ (vrow&7))*8)];   \
        OACC_[nt] = __builtin_amdgcn_mfma_f32_16x16x32_bf16(pa, vf, OACC_[nt], 0,0,0);   \
      }                                                                                  \
      __builtin_amdgcn_s_setprio(0);                                                     \
    }                                                                                    \
  }

// tile order mirrors round 8: stage(t+1) -> vmcnt -> barrier -> combine/raw/compute -> barrier
#define TILE(kt_, cur_, RP_, DOSTAGE, DORAW, VMFULL)                                     \
  {                                                                                      \
    if (DOSTAGE) ATTN_STAGE((cur_)^1, (kt_)+1)                                           \
    if (VMFULL) { asm volatile("s_waitcnt vmcnt(5)" ::: "memory"); }                     \
    else        { asm volatile("s_waitcnt vmcnt(0)" ::: "memory"); }                     \
    __builtin_amdgcn_s_barrier();                                                        \
    ATTN_COMBINE(RP_, cur_)                                                              \
    if (DORAW) ATTN_RAW(RP_, (kt_)+2)                                                    \
    COMPUTE_BATCH(cur_, 0, qfA0, qfA1, oaccA, psumA)                                     \
    COMPUTE_BATCH(cur_, 1, qfB0, qfB1, oaccB, psumB)                                     \
    __builtin_amdgcn_s_barrier();                                                        \
  }

  // prologue: S(0)3, R_A(0)2, R_B(1)2  -> 7 outstanding
  ATTN_STAGE(0, 0)
  ATTN_RAW(RA, 0)
  ATTN_RAW(RB, 1)

  // steady queue at gate: R(t)2 + S(t)3 + R(t+1)2 + S(t+1)3 = 10; vmcnt(5) retires {R(t),S(t)}
  for (int kb=0; kb<30; kb+=2){
    TILE(kb+0, 0, RA, 1, 1, 1)
    TILE(kb+1, 1, RB, 1, 1, 1)
  }
  TILE(30, 0, RA, 1, 0, 1)
  TILE(31, 1, RB, 0, 0, 0)

  // finalize both batches
  {
    float lsum = psumA;
    lsum += __shfl_xor(lsum, 16);
    lsum += __shfl_xor(lsum, 32);
    #pragma unroll
    for (int r=0;r<4;r++){
      float lr = __shfl(lsum, lg*4 + r);
      float linv = 1.f/lr;
      int qrow = q0 + lg*4 + r;
      #pragma unroll
      for (int nt=0;nt<4;nt++)
        Oout[((size_t)qrow)*2048 + h*64 + nt*16 + lq] = f2bf(oaccA[nt][r]*linv);
    }
  }
  {
    float lsum = psumB;
    lsum += __shfl_xor(lsum, 16);
    lsum += __shfl_xor(lsum, 32);
    #pragma unroll
    for (int r=0;r<4;r++){
      float lr = __shfl(lsum, lg*4 + r);
      float linv = 1.f/lr;
      int qrow = q0 + lg*4 + r;
      #pragma unroll
      for (int nt=0;nt<4;nt++)
        Oout[((size_t)(1024 + qrow))*2048 + h*64 + nt*16 + lq] = f2bf(oaccB[nt][r]*linv);
    }
  }
#undef TILE
#undef COMPUTE_BATCH
#undef ATTN_COMBINE
#undef ATTN_RAW
#undef ATTN_STAGE
}

extern "C" void kernel_launch(void* const* d_in, const int* in_sizes, int n_in,
                              void* d_out, int out_size, void* d_ws, size_t ws_size,
                              hipStream_t stream){
  (void)in_sizes; (void)n_in; (void)out_size; (void)ws_size;
  const float* query = (const float*)d_in[0];
  const float* key   = (const float*)d_in[1];
  const float* value = (const float*)d_in[2];
  const float* mask  = (const float*)d_in[3];
  const float* pbias = (const float*)d_in[4];
  const float* Wq = (const float*)d_in[5];
  const float* bq = (const float*)d_in[6];
  const float* Wk = (const float*)d_in[7];
  const float* bk = (const float*)d_in[8];
  const float* Wv = (const float*)d_in[9];
  const float* bv = (const float*)d_in[10];
  const float* Wo = (const float*)d_in[11];
  const float* bo = (const float*)d_in[12];
  char* ws = (char*)d_ws;
  const size_t MB = (size_t)1<<20;
  unsigned short* qbf = (unsigned short*)(ws + 0*MB);
  unsigned short* kbf = (unsigned short*)(ws + 8*MB);
  unsigned short* vbf = (unsigned short*)(ws + 16*MB);
  unsigned short* WqT = (unsigned short*)(ws + 24*MB);
  unsigned short* WkT = (unsigned short*)(ws + 32*MB);
  unsigned short* WvT = (unsigned short*)(ws + 34*MB);
  unsigned short* WoT = (unsigned short*)(ws + 36*MB);
  unsigned short* Qp  = (unsigned short*)(ws + 44*MB);
  unsigned short* Kp  = (unsigned short*)(ws + 52*MB);
  unsigned short* VTb = (unsigned short*)(ws + 54*MB);
  unsigned short* Aout= (unsigned short*)(ws + 56*MB);

  prep_k<<<8704,256,0,stream>>>(query, key, value, qbf, kbf, vbf,
                                Wq, Wk, Wv, Wo, WqT, WkT, WvT, WoT);
  qkv64<<<1536,256,0,stream>>>(qbf, kbf, vbf, WqT, WkT, WvT, bq, bk, bv, Qp, Kp, VTb);
  attn_k<<<256,512,0,stream>>>(Qp, Kp, VTb, pbias, mask, Aout);
  oproj64<<<dim3(32,32),256,0,stream>>>(Aout, WoT, bo, (float*)d_out);
}